// Round 8
// baseline (1596.531 us; speedup 1.0000x reference)
//
#include <hip/hip_runtime.h>
#include <math.h>

#define NNODES 50000
#define NEDGES 1600000
#define DOUT 256
#define NEG_SLOPE 0.2f
#define SCANB ((NNODES + 255) / 256)
#define NB ((NNODES + 255) / 256)   // dst buckets of 256 nodes
#define BCAP 10240                  // bucket capacity (mean ~8420, 20σ margin)

typedef __attribute__((ext_vector_type(8))) short short8;
typedef __attribute__((ext_vector_type(8))) unsigned short u16x8;
typedef __attribute__((ext_vector_type(4))) float f32x4;

__device__ __forceinline__ float lrelu(float e) { return e > 0.f ? e : NEG_SLOPE * e; }
__device__ __forceinline__ float b2f(unsigned short u) {
  union { unsigned u; float f; } c; c.u = ((unsigned)u) << 16; return c.f;
}
__device__ __forceinline__ unsigned short f2b(float f) {
  union { float f; unsigned u; } c; c.f = f;
  return (unsigned short)((c.u + 0x7fffu + ((c.u >> 16) & 1u)) >> 16);
}

// ---------------- CSR build (bucketed) ----------------
// Pass A: histogram per-dst degree AND append (src,dst) to per-bucket regions.
__global__ __launch_bounds__(256) void k_bucket(const int* __restrict__ ei,
                                                int* __restrict__ deg,
                                                int* __restrict__ bcnt,
                                                int2* __restrict__ bbuf) {
  int e = blockIdx.x * 256 + threadIdx.x;
  const int EP = NEDGES + NNODES;
  if (e >= EP) return;
  int src, dst;
  if (e < NEDGES) { src = ei[e]; dst = ei[NEDGES + e]; }
  else            { src = e - NEDGES; dst = src; }
  atomicAdd(&deg[dst], 1);
  const int b = dst >> 8;
  const int pos = atomicAdd(&bcnt[b], 1);
  bbuf[(size_t)b * BCAP + pos] = make_int2(src, dst);
}

__global__ __launch_bounds__(256) void k_scan1(const int* __restrict__ deg,
                                               int* __restrict__ rowptr,
                                               int* __restrict__ bsum) {
  __shared__ int wsum[4];
  const int t = threadIdx.x, lane = t & 63, w = t >> 6;
  const int i = blockIdx.x * 256 + t;
  int x = (i < NNODES) ? deg[i] : 0;
  #pragma unroll
  for (int off = 1; off < 64; off <<= 1) {
    int y = __shfl_up(x, off);
    if (lane >= off) x += y;
  }
  if (lane == 63) wsum[w] = x;
  __syncthreads();
  int s0 = wsum[0], s1 = wsum[1], s2 = wsum[2], s3 = wsum[3];
  int woff = (w > 0 ? s0 : 0) + (w > 1 ? s1 : 0) + (w > 2 ? s2 : 0);
  if (i < NNODES) rowptr[i + 1] = woff + x;
  if (t == 255) bsum[blockIdx.x] = woff + x;
}

__global__ __launch_bounds__(256) void k_scan2(int* __restrict__ bsum,
                                               int* __restrict__ bexcl) {
  __shared__ int wsum[4];
  const int t = threadIdx.x, lane = t & 63, w = t >> 6;
  int v = (t < SCANB) ? bsum[t] : 0;
  int x = v;
  #pragma unroll
  for (int off = 1; off < 64; off <<= 1) {
    int y = __shfl_up(x, off);
    if (lane >= off) x += y;
  }
  if (lane == 63) wsum[w] = x;
  __syncthreads();
  int s0 = wsum[0], s1 = wsum[1], s2 = wsum[2], s3 = wsum[3];
  int woff = (w > 0 ? s0 : 0) + (w > 1 ? s1 : 0) + (w > 2 ? s2 : 0);
  if (t < SCANB) bexcl[t] = woff + x - v;
}

__global__ __launch_bounds__(256) void k_scan3(int* __restrict__ rowptr,
                                               const int* __restrict__ bexcl) {
  const int i = blockIdx.x * 256 + threadIdx.x;
  if (i == 0) rowptr[0] = 0;
  if (i < NNODES) rowptr[i + 1] += bexcl[blockIdx.x];
}

// Pass B: one block per bucket; LDS fill counters; esrc writes land in a
// contiguous ~deg*256*4B region -> L2 line reuse (no 16x write amplification).
__global__ __launch_bounds__(256) void k_unbucket(const int2* __restrict__ bbuf,
                                                  const int* __restrict__ bcnt,
                                                  const int* __restrict__ rowptr,
                                                  int* __restrict__ esrc) {
  __shared__ int fill[256];
  const int b = blockIdx.x;
  fill[threadIdx.x] = 0;
  __syncthreads();
  const int cnt = bcnt[b];
  const int2* __restrict__ bp = bbuf + (size_t)b * BCAP;
  for (int i = threadIdx.x; i < cnt; i += 256) {
    const int2 sd = bp[i];
    const int pos = rowptr[sd.y] + atomicAdd(&fill[sd.y & 255], 1);
    esrc[pos] = sd.x;
  }
}

// ---------------- casts ----------------
__global__ __launch_bounds__(256) void k_castX(const float4* __restrict__ in,
                                               ushort4* __restrict__ outb, int n4) {
  for (int i = blockIdx.x * 256 + threadIdx.x; i < n4; i += gridDim.x * 256) {
    float4 v = in[i];
    ushort4 o;
    o.x = f2b(v.x); o.y = f2b(v.y); o.z = f2b(v.z); o.w = f2b(v.w);
    outb[i] = o;
  }
}

// W [DIN][DOUT] fp32 -> Wt [DOUT][DIN] bf16
template<int DIN>
__global__ __launch_bounds__(256) void k_castW(const float* __restrict__ W,
                                               unsigned short* __restrict__ Wt) {
  int idx = blockIdx.x * 256 + threadIdx.x;
  if (idx >= DIN * DOUT) return;
  int k = idx / DOUT, n = idx % DOUT;
  Wt[n * DIN + k] = f2b(W[idx]);
}

// ---------------- MFMA GEMM: H = A @ W, + fused attention logits ----------------
template<int DIN>
__global__ __launch_bounds__(256) void k_gemm_mfma(
    const unsigned short* __restrict__ Ab, const unsigned short* __restrict__ Wt,
    const float* __restrict__ a_src, const float* __restrict__ a_dst,
    unsigned short* __restrict__ Hb, float* __restrict__ asn, float* __restrict__ adn)
{
  __shared__ float s_ps[4][64];
  __shared__ float s_pd[4][64];
  const int lane = threadIdx.x & 63;
  const int wv = threadIdx.x >> 6;
  const int row0 = blockIdx.x * 64;
  const int col0 = wv * 64;
  const int lr = lane & 15;
  const int lk = lane >> 4;

  f32x4 acc[4][4];
  #pragma unroll
  for (int m = 0; m < 4; ++m)
    #pragma unroll
    for (int n = 0; n < 4; ++n)
      acc[m][n] = (f32x4){0.f, 0.f, 0.f, 0.f};

  const unsigned short* arow[4];
  #pragma unroll
  for (int m = 0; m < 4; ++m) {
    int r = row0 + m * 16 + lr;
    if (r > NNODES - 1) r = NNODES - 1;
    arow[m] = Ab + (size_t)r * DIN + lk * 8;
  }
  const unsigned short* brow[4];
  #pragma unroll
  for (int n = 0; n < 4; ++n)
    brow[n] = Wt + (size_t)(col0 + n * 16 + lr) * DIN + lk * 8;

  for (int k = 0; k < DIN; k += 32) {
    short8 aF[4], bF[4];
    #pragma unroll
    for (int m = 0; m < 4; ++m)
      aF[m] = *reinterpret_cast<const short8*>(arow[m] + k);
    #pragma unroll
    for (int n = 0; n < 4; ++n)
      bF[n] = *reinterpret_cast<const short8*>(brow[n] + k);
    #pragma unroll
    for (int m = 0; m < 4; ++m)
      #pragma unroll
      for (int n = 0; n < 4; ++n)
        acc[m][n] = __builtin_amdgcn_mfma_f32_16x16x32_bf16(aF[m], bF[n], acc[m][n], 0, 0, 0);
  }

  float asv[4], adv[4];
  #pragma unroll
  for (int n = 0; n < 4; ++n) {
    int c = col0 + n * 16 + lr;
    asv[n] = a_src[c];
    adv[n] = a_dst[c];
  }

  #pragma unroll
  for (int m = 0; m < 4; ++m) {
    float ps[4] = {0.f, 0.f, 0.f, 0.f};
    float pd[4] = {0.f, 0.f, 0.f, 0.f};
    #pragma unroll
    for (int n = 0; n < 4; ++n) {
      int col = col0 + n * 16 + lr;
      #pragma unroll
      for (int j = 0; j < 4; ++j) {
        int row = row0 + m * 16 + lk * 4 + j;
        float v = acc[m][n][j];
        if (row < NNODES)
          Hb[(size_t)row * DOUT + col] = f2b(v);
        ps[j] = fmaf(v, asv[n], ps[j]);
        pd[j] = fmaf(v, adv[n], pd[j]);
      }
    }
    #pragma unroll
    for (int off = 1; off < 16; off <<= 1) {
      #pragma unroll
      for (int j = 0; j < 4; ++j) {
        ps[j] += __shfl_xor(ps[j], off);
        pd[j] += __shfl_xor(pd[j], off);
      }
    }
    if (lr == 0) {
      #pragma unroll
      for (int j = 0; j < 4; ++j) {
        s_ps[wv][m * 16 + lk * 4 + j] = ps[j];
        s_pd[wv][m * 16 + lk * 4 + j] = pd[j];
      }
    }
  }

  __syncthreads();
  const int t = threadIdx.x;
  if (t < 64) {
    int row = row0 + t;
    if (row < NNODES) {
      asn[row] = s_ps[0][t] + s_ps[1][t] + s_ps[2][t] + s_ps[3][t];
      adn[row] = s_pd[0][t] + s_pd[1][t] + s_pd[2][t] + s_pd[3][t];
    }
  }
}

// ---------------- attention softmax + aggregation (single sweep) ----------------
template<int MODE>
__global__ __launch_bounds__(256) void k_agg(
    const unsigned short* __restrict__ Hb, const int* __restrict__ rowptr,
    const int* __restrict__ esrc, const float* __restrict__ asn,
    const float* __restrict__ adn, const float* __restrict__ bias,
    const float* __restrict__ base, float* __restrict__ out,
    unsigned short* __restrict__ outb)
{
  const int lane = threadIdx.x & 63;
  const int wv = threadIdx.x >> 6;
  const int n = blockIdx.x * 4 + wv;
  if (n >= NNODES) return;
  const int start = rowptr[n];
  const int end = rowptr[n + 1];
  const float adv = adn[n];

  const int q = lane >> 4;
  const int c16 = lane & 15;
  const unsigned short* __restrict__ hb0 = Hb + c16 * 8;
  const unsigned short* __restrict__ hb1 = Hb + 128 + c16 * 8;

  float m = -1e30f, s = 0.f;
  float acc[16];
  #pragma unroll
  for (int k = 0; k < 16; ++k) acc[k] = 0.f;

  for (int c0 = start; c0 < end; c0 += 64) {
    const int i = c0 + lane;
    int msrc = 0;
    float e = -1e30f;
    if (i < end) {
      msrc = esrc[i];
      e = lrelu(asn[msrc] + adv);
    }
    float cm = e;
    #pragma unroll
    for (int off = 32; off > 0; off >>= 1) cm = fmaxf(cm, __shfl_xor(cm, off));
    const float mn = fmaxf(m, cm);
    const float resc = __expf(m - mn);
    s *= resc;
    #pragma unroll
    for (int k = 0; k < 16; ++k) acc[k] *= resc;
    m = mn;
    float p = __expf(e - mn);
    float cs = p;
    #pragma unroll
    for (int off = 32; off > 0; off >>= 1) cs += __shfl_xor(cs, off);
    s += cs;

    const int cnt = min(64, end - c0);
    const int qcnt = (cnt + 3) >> 2;
    for (int jj = 0; jj < qcnt; jj += 2) {
      const int e0 = 4 * jj + q;
      const int e1 = e0 + 4;
      const int s0 = (e0 < cnt) ? e0 : 0;
      const int s1 = (e1 < cnt) ? e1 : 0;
      float a0 = __shfl(p, s0);
      const int sj0 = __shfl(msrc, s0);
      float a1 = __shfl(p, s1);
      const int sj1 = __shfl(msrc, s1);
      if (e0 >= cnt) a0 = 0.f;
      if (jj + 1 >= qcnt || e1 >= cnt) a1 = 0.f;
      const u16x8 h00 = *reinterpret_cast<const u16x8*>(hb0 + (size_t)sj0 * DOUT);
      const u16x8 h01 = *reinterpret_cast<const u16x8*>(hb1 + (size_t)sj0 * DOUT);
      const u16x8 h10 = *reinterpret_cast<const u16x8*>(hb0 + (size_t)sj1 * DOUT);
      const u16x8 h11 = *reinterpret_cast<const u16x8*>(hb1 + (size_t)sj1 * DOUT);
      #pragma unroll
      for (int k = 0; k < 8; ++k) {
        acc[k]     = fmaf(a0, b2f((unsigned short)h00[k]), acc[k]);
        acc[k + 8] = fmaf(a0, b2f((unsigned short)h01[k]), acc[k + 8]);
      }
      #pragma unroll
      for (int k = 0; k < 8; ++k) {
        acc[k]     = fmaf(a1, b2f((unsigned short)h10[k]), acc[k]);
        acc[k + 8] = fmaf(a1, b2f((unsigned short)h11[k]), acc[k + 8]);
      }
    }
  }

  #pragma unroll
  for (int k = 0; k < 16; ++k) {
    acc[k] += __shfl_xor(acc[k], 16);
    acc[k] += __shfl_xor(acc[k], 32);
  }

  if (lane < 16) {
    const float inv = 1.f / (s + 1e-16f);
    const int cb = c16 * 8;
    float o[16];
    #pragma unroll
    for (int k = 0; k < 8; ++k) {
      o[k]     = fmaxf(acc[k] * inv + bias[cb + k], 0.f);
      o[k + 8] = fmaxf(acc[k + 8] * inv + bias[128 + cb + k], 0.f);
    }
    if (MODE == 1) {
      #pragma unroll
      for (int k = 0; k < 8; ++k) {
        o[k]     += base[(size_t)n * DOUT + cb + k];
        o[k + 8] += base[(size_t)n * DOUT + 128 + cb + k];
      }
    }
    *reinterpret_cast<float4*>(out + (size_t)n * DOUT + cb)           = make_float4(o[0], o[1], o[2], o[3]);
    *reinterpret_cast<float4*>(out + (size_t)n * DOUT + cb + 4)       = make_float4(o[4], o[5], o[6], o[7]);
    *reinterpret_cast<float4*>(out + (size_t)n * DOUT + 128 + cb)     = make_float4(o[8], o[9], o[10], o[11]);
    *reinterpret_cast<float4*>(out + (size_t)n * DOUT + 128 + cb + 4) = make_float4(o[12], o[13], o[14], o[15]);
    u16x8 ob0, ob1;
    #pragma unroll
    for (int k = 0; k < 8; ++k) { ob0[k] = f2b(o[k]); ob1[k] = f2b(o[k + 8]); }
    *reinterpret_cast<u16x8*>(outb + (size_t)n * DOUT + cb)       = ob0;
    *reinterpret_cast<u16x8*>(outb + (size_t)n * DOUT + 128 + cb) = ob1;
  }
}

// ---------------- launch ----------------
extern "C" void kernel_launch(void* const* d_in, const int* in_sizes, int n_in,
                              void* d_out, int out_size, void* d_ws, size_t ws_size,
                              hipStream_t stream) {
  const float* x   = (const float*)d_in[0];
  const int*   ei  = (const int*)d_in[1];
  const float* W1  = (const float*)d_in[2];
  const float* as1 = (const float*)d_in[3];
  const float* ad1 = (const float*)d_in[4];
  const float* b1  = (const float*)d_in[5];
  const float* W2  = (const float*)d_in[6];
  const float* as2 = (const float*)d_in[7];
  const float* ad2 = (const float*)d_in[8];
  const float* b2  = (const float*)d_in[9];
  const float* W3  = (const float*)d_in[10];
  const float* as3 = (const float*)d_in[11];
  const float* ad3 = (const float*)d_in[12];
  const float* b3  = (const float*)d_in[13];
  float* out = (float*)d_out;   // doubles as fp32 layer output

  char* ws = (char*)d_ws;
  size_t off = 0;
  auto alloc = [&](size_t bytes) -> void* {
    void* p = ws + off;
    off = (off + bytes + 255) & ~(size_t)255;
    return p;
  };
  unsigned short* Xb   = (unsigned short*)alloc((size_t)NNODES * 512 * sizeof(unsigned short));
  unsigned short* Hb   = (unsigned short*)alloc((size_t)NNODES * DOUT * sizeof(unsigned short));
  unsigned short* W1t  = (unsigned short*)alloc((size_t)512 * DOUT * sizeof(unsigned short));
  unsigned short* W2t  = (unsigned short*)alloc((size_t)DOUT * DOUT * sizeof(unsigned short));
  unsigned short* W3t  = (unsigned short*)alloc((size_t)DOUT * DOUT * sizeof(unsigned short));
  float* asn  = (float*)alloc(NNODES * sizeof(float));
  float* adn  = (float*)alloc(NNODES * sizeof(float));
  int*   deg  = (int*)alloc(NNODES * sizeof(int));
  int*   rowptr = (int*)alloc((NNODES + 1) * sizeof(int));
  int*   bsum = (int*)alloc(SCANB * sizeof(int));
  int*   bexcl = (int*)alloc(SCANB * sizeof(int));
  int*   bcnt = (int*)alloc(NB * sizeof(int));
  int*   esrc = (int*)alloc((size_t)(NEDGES + NNODES) * sizeof(int));
  int2*  bbuf = (int2*)alloc((size_t)NB * BCAP * sizeof(int2));

  const int EP = NEDGES + NNODES;
  hipMemsetAsync(deg, 0, NNODES * sizeof(int), stream);
  hipMemsetAsync(bcnt, 0, NB * sizeof(int), stream);

  // CSR build: bucket (hist fused) -> scan -> unbucket
  k_bucket<<<(EP + 255) / 256, 256, 0, stream>>>(ei, deg, bcnt, bbuf);
  k_scan1<<<SCANB, 256, 0, stream>>>(deg, rowptr, bsum);
  k_scan2<<<1, 256, 0, stream>>>(bsum, bexcl);
  k_scan3<<<SCANB, 256, 0, stream>>>(rowptr, bexcl);
  k_unbucket<<<NB, 256, 0, stream>>>(bbuf, bcnt, rowptr, esrc);

  // casts
  k_castX<<<2048, 256, 0, stream>>>((const float4*)x, (ushort4*)Xb, NNODES * 512 / 4);
  k_castW<512><<<(512 * DOUT + 255) / 256, 256, 0, stream>>>(W1, W1t);
  k_castW<256><<<(256 * DOUT + 255) / 256, 256, 0, stream>>>(W2, W2t);
  k_castW<256><<<(256 * DOUT + 255) / 256, 256, 0, stream>>>(W3, W3t);

  const int gemmGrid = (NNODES + 63) / 64;
  const int aggGrid  = (NNODES + 3) / 4;

  // layer 1
  k_gemm_mfma<512><<<gemmGrid, 256, 0, stream>>>(Xb, W1t, as1, ad1, Hb, asn, adn);
  k_agg<0><<<aggGrid, 256, 0, stream>>>(Hb, rowptr, esrc, asn, adn, b1, nullptr, out, Xb);
  // layer 2 (Xb now holds bf16 of layer-1 output)
  k_gemm_mfma<256><<<gemmGrid, 256, 0, stream>>>(Xb, W2t, as2, ad2, Hb, asn, adn);
  k_agg<1><<<aggGrid, 256, 0, stream>>>(Hb, rowptr, esrc, asn, adn, b2, out, out, Xb);
  // layer 3
  k_gemm_mfma<256><<<gemmGrid, 256, 0, stream>>>(Xb, W3t, as3, ad3, Hb, asn, adn);
  k_agg<1><<<aggGrid, 256, 0, stream>>>(Hb, rowptr, esrc, asn, adn, b3, out, out, Xb);
}

// Round 9
// 649.662 us; speedup vs baseline: 2.4575x; 2.4575x over previous
//
#include <hip/hip_runtime.h>
#include <math.h>

#define NNODES 50000
#define NEDGES 1600000
#define DOUT 256
#define NEG_SLOPE 0.2f
#define SCANB ((NNODES + 255) / 256)
#define NB ((NNODES + 255) / 256)   // dst buckets of 256 nodes (196)
#define BCAP 10240                  // bucket capacity (mean ~8420, >15 sigma margin)
#define CHUNK 8192                  // edges per k_bucket block

typedef __attribute__((ext_vector_type(8))) short short8;
typedef __attribute__((ext_vector_type(8))) unsigned short u16x8;
typedef __attribute__((ext_vector_type(4))) float f32x4;

__device__ __forceinline__ float lrelu(float e) { return e > 0.f ? e : NEG_SLOPE * e; }
__device__ __forceinline__ float b2f(unsigned short u) {
  union { unsigned u; float f; } c; c.u = ((unsigned)u) << 16; return c.f;
}
__device__ __forceinline__ unsigned short f2b(float f) {
  union { float f; unsigned u; } c; c.f = f;
  return (unsigned short)((c.u + 0x7fffu + ((c.u >> 16) & 1u)) >> 16);
}

// ---------------- CSR build (bucketed, LDS-hist reserve) ----------------
// Pass A: per-block LDS histogram over NB buckets, ONE global reserve atomic
// per (block,bucket), then direct writes into the block's private contiguous
// sub-segment. All writers of a bbuf line are in the same block -> same XCD
// L2 merges partial-line writes (no 16x amplification). deg hist fused.
__global__ __launch_bounds__(256) void k_bucket(const int* __restrict__ ei,
                                                int* __restrict__ deg,
                                                int* __restrict__ bcnt,
                                                int2* __restrict__ bbuf) {
  __shared__ int hcnt[NB];
  __shared__ int lpos[NB];
  const int t = threadIdx.x;
  const int e0 = blockIdx.x * CHUNK;
  const int EP = NEDGES + NNODES;
  const int ecnt = min(CHUNK, EP - e0);
  for (int i = t; i < NB; i += 256) hcnt[i] = 0;
  __syncthreads();
  for (int i = t; i < ecnt; i += 256) {
    const int e = e0 + i;
    int src, dst;
    if (e < NEDGES) { src = ei[e]; dst = ei[NEDGES + e]; }
    else            { src = e - NEDGES; dst = src; }
    atomicAdd(&deg[dst], 1);
    atomicAdd(&hcnt[dst >> 8], 1);
  }
  __syncthreads();
  for (int b = t; b < NB; b += 256) {
    const int c = hcnt[b];
    lpos[b] = (c > 0) ? atomicAdd(&bcnt[b], c) : 0;
  }
  __syncthreads();
  for (int i = t; i < ecnt; i += 256) {
    const int e = e0 + i;
    int src, dst;
    if (e < NEDGES) { src = ei[e]; dst = ei[NEDGES + e]; }
    else            { src = e - NEDGES; dst = src; }
    const int b = dst >> 8;
    const int p = atomicAdd(&lpos[b], 1);
    bbuf[(size_t)b * BCAP + p] = make_int2(src, dst);
  }
}

__global__ __launch_bounds__(256) void k_scan1(const int* __restrict__ deg,
                                               int* __restrict__ rowptr,
                                               int* __restrict__ bsum) {
  __shared__ int wsum[4];
  const int t = threadIdx.x, lane = t & 63, w = t >> 6;
  const int i = blockIdx.x * 256 + t;
  int x = (i < NNODES) ? deg[i] : 0;
  #pragma unroll
  for (int off = 1; off < 64; off <<= 1) {
    int y = __shfl_up(x, off);
    if (lane >= off) x += y;
  }
  if (lane == 63) wsum[w] = x;
  __syncthreads();
  int s0 = wsum[0], s1 = wsum[1], s2 = wsum[2], s3 = wsum[3];
  int woff = (w > 0 ? s0 : 0) + (w > 1 ? s1 : 0) + (w > 2 ? s2 : 0);
  if (i < NNODES) rowptr[i + 1] = woff + x;
  if (t == 255) bsum[blockIdx.x] = woff + x;
}

__global__ __launch_bounds__(256) void k_scan2(int* __restrict__ bsum,
                                               int* __restrict__ bexcl) {
  __shared__ int wsum[4];
  const int t = threadIdx.x, lane = t & 63, w = t >> 6;
  int v = (t < SCANB) ? bsum[t] : 0;
  int x = v;
  #pragma unroll
  for (int off = 1; off < 64; off <<= 1) {
    int y = __shfl_up(x, off);
    if (lane >= off) x += y;
  }
  if (lane == 63) wsum[w] = x;
  __syncthreads();
  int s0 = wsum[0], s1 = wsum[1], s2 = wsum[2], s3 = wsum[3];
  int woff = (w > 0 ? s0 : 0) + (w > 1 ? s1 : 0) + (w > 2 ? s2 : 0);
  if (t < SCANB) bexcl[t] = woff + x - v;
}

__global__ __launch_bounds__(256) void k_scan3(int* __restrict__ rowptr,
                                               const int* __restrict__ bexcl) {
  const int i = blockIdx.x * 256 + threadIdx.x;
  if (i == 0) rowptr[0] = 0;
  if (i < NNODES) rowptr[i + 1] += bexcl[blockIdx.x];
}

// Pass B: one block per bucket; LDS fill counters; esrc writes land in a
// contiguous ~33KB region from a single block -> L2-merged full lines.
__global__ __launch_bounds__(256) void k_unbucket(const int2* __restrict__ bbuf,
                                                  const int* __restrict__ bcnt,
                                                  const int* __restrict__ rowptr,
                                                  int* __restrict__ esrc) {
  __shared__ int fill[256];
  const int b = blockIdx.x;
  fill[threadIdx.x] = 0;
  __syncthreads();
  const int cnt = bcnt[b];
  const int2* __restrict__ bp = bbuf + (size_t)b * BCAP;
  for (int i = threadIdx.x; i < cnt; i += 256) {
    const int2 sd = bp[i];
    const int pos = rowptr[sd.y] + atomicAdd(&fill[sd.y & 255], 1);
    esrc[pos] = sd.x;
  }
}

// ---------------- casts ----------------
__global__ __launch_bounds__(256) void k_castX(const float4* __restrict__ in,
                                               ushort4* __restrict__ outb, int n4) {
  for (int i = blockIdx.x * 256 + threadIdx.x; i < n4; i += gridDim.x * 256) {
    float4 v = in[i];
    ushort4 o;
    o.x = f2b(v.x); o.y = f2b(v.y); o.z = f2b(v.z); o.w = f2b(v.w);
    outb[i] = o;
  }
}

// W [DIN][DOUT] fp32 -> Wt [DOUT][DIN] bf16
template<int DIN>
__global__ __launch_bounds__(256) void k_castW(const float* __restrict__ W,
                                               unsigned short* __restrict__ Wt) {
  int idx = blockIdx.x * 256 + threadIdx.x;
  if (idx >= DIN * DOUT) return;
  int k = idx / DOUT, n = idx % DOUT;
  Wt[n * DIN + k] = f2b(W[idx]);
}

// ---------------- MFMA GEMM: H = A @ W, + fused attention logits ----------------
template<int DIN>
__global__ __launch_bounds__(256) void k_gemm_mfma(
    const unsigned short* __restrict__ Ab, const unsigned short* __restrict__ Wt,
    const float* __restrict__ a_src, const float* __restrict__ a_dst,
    unsigned short* __restrict__ Hb, float* __restrict__ asn, float* __restrict__ adn)
{
  __shared__ float s_ps[4][64];
  __shared__ float s_pd[4][64];
  const int lane = threadIdx.x & 63;
  const int wv = threadIdx.x >> 6;
  const int row0 = blockIdx.x * 64;
  const int col0 = wv * 64;
  const int lr = lane & 15;
  const int lk = lane >> 4;

  f32x4 acc[4][4];
  #pragma unroll
  for (int m = 0; m < 4; ++m)
    #pragma unroll
    for (int n = 0; n < 4; ++n)
      acc[m][n] = (f32x4){0.f, 0.f, 0.f, 0.f};

  const unsigned short* arow[4];
  #pragma unroll
  for (int m = 0; m < 4; ++m) {
    int r = row0 + m * 16 + lr;
    if (r > NNODES - 1) r = NNODES - 1;
    arow[m] = Ab + (size_t)r * DIN + lk * 8;
  }
  const unsigned short* brow[4];
  #pragma unroll
  for (int n = 0; n < 4; ++n)
    brow[n] = Wt + (size_t)(col0 + n * 16 + lr) * DIN + lk * 8;

  for (int k = 0; k < DIN; k += 32) {
    short8 aF[4], bF[4];
    #pragma unroll
    for (int m = 0; m < 4; ++m)
      aF[m] = *reinterpret_cast<const short8*>(arow[m] + k);
    #pragma unroll
    for (int n = 0; n < 4; ++n)
      bF[n] = *reinterpret_cast<const short8*>(brow[n] + k);
    #pragma unroll
    for (int m = 0; m < 4; ++m)
      #pragma unroll
      for (int n = 0; n < 4; ++n)
        acc[m][n] = __builtin_amdgcn_mfma_f32_16x16x32_bf16(aF[m], bF[n], acc[m][n], 0, 0, 0);
  }

  float asv[4], adv[4];
  #pragma unroll
  for (int n = 0; n < 4; ++n) {
    int c = col0 + n * 16 + lr;
    asv[n] = a_src[c];
    adv[n] = a_dst[c];
  }

  #pragma unroll
  for (int m = 0; m < 4; ++m) {
    float ps[4] = {0.f, 0.f, 0.f, 0.f};
    float pd[4] = {0.f, 0.f, 0.f, 0.f};
    #pragma unroll
    for (int n = 0; n < 4; ++n) {
      int col = col0 + n * 16 + lr;
      #pragma unroll
      for (int j = 0; j < 4; ++j) {
        int row = row0 + m * 16 + lk * 4 + j;
        float v = acc[m][n][j];
        if (row < NNODES)
          Hb[(size_t)row * DOUT + col] = f2b(v);
        ps[j] = fmaf(v, asv[n], ps[j]);
        pd[j] = fmaf(v, adv[n], pd[j]);
      }
    }
    #pragma unroll
    for (int off = 1; off < 16; off <<= 1) {
      #pragma unroll
      for (int j = 0; j < 4; ++j) {
        ps[j] += __shfl_xor(ps[j], off);
        pd[j] += __shfl_xor(pd[j], off);
      }
    }
    if (lr == 0) {
      #pragma unroll
      for (int j = 0; j < 4; ++j) {
        s_ps[wv][m * 16 + lk * 4 + j] = ps[j];
        s_pd[wv][m * 16 + lk * 4 + j] = pd[j];
      }
    }
  }

  __syncthreads();
  const int t = threadIdx.x;
  if (t < 64) {
    int row = row0 + t;
    if (row < NNODES) {
      asn[row] = s_ps[0][t] + s_ps[1][t] + s_ps[2][t] + s_ps[3][t];
      adn[row] = s_pd[0][t] + s_pd[1][t] + s_pd[2][t] + s_pd[3][t];
    }
  }
}

// ---------------- attention softmax + aggregation (single sweep) ----------------
template<int MODE>
__global__ __launch_bounds__(256) void k_agg(
    const unsigned short* __restrict__ Hb, const int* __restrict__ rowptr,
    const int* __restrict__ esrc, const float* __restrict__ asn,
    const float* __restrict__ adn, const float* __restrict__ bias,
    const float* __restrict__ base, float* __restrict__ out,
    unsigned short* __restrict__ outb)
{
  const int lane = threadIdx.x & 63;
  const int wv = threadIdx.x >> 6;
  const int n = blockIdx.x * 4 + wv;
  if (n >= NNODES) return;
  const int start = rowptr[n];
  const int end = rowptr[n + 1];
  const float adv = adn[n];

  const int q = lane >> 4;
  const int c16 = lane & 15;
  const unsigned short* __restrict__ hb0 = Hb + c16 * 8;
  const unsigned short* __restrict__ hb1 = Hb + 128 + c16 * 8;

  float m = -1e30f, s = 0.f;
  float acc[16];
  #pragma unroll
  for (int k = 0; k < 16; ++k) acc[k] = 0.f;

  for (int c0 = start; c0 < end; c0 += 64) {
    const int i = c0 + lane;
    int msrc = 0;
    float e = -1e30f;
    if (i < end) {
      msrc = esrc[i];
      e = lrelu(asn[msrc] + adv);
    }
    float cm = e;
    #pragma unroll
    for (int off = 32; off > 0; off >>= 1) cm = fmaxf(cm, __shfl_xor(cm, off));
    const float mn = fmaxf(m, cm);
    const float resc = __expf(m - mn);
    s *= resc;
    #pragma unroll
    for (int k = 0; k < 16; ++k) acc[k] *= resc;
    m = mn;
    float p = __expf(e - mn);
    float cs = p;
    #pragma unroll
    for (int off = 32; off > 0; off >>= 1) cs += __shfl_xor(cs, off);
    s += cs;

    const int cnt = min(64, end - c0);
    const int qcnt = (cnt + 3) >> 2;
    for (int jj = 0; jj < qcnt; jj += 2) {
      const int e0 = 4 * jj + q;
      const int e1 = e0 + 4;
      const int s0 = (e0 < cnt) ? e0 : 0;
      const int s1 = (e1 < cnt) ? e1 : 0;
      float a0 = __shfl(p, s0);
      const int sj0 = __shfl(msrc, s0);
      float a1 = __shfl(p, s1);
      const int sj1 = __shfl(msrc, s1);
      if (e0 >= cnt) a0 = 0.f;
      if (jj + 1 >= qcnt || e1 >= cnt) a1 = 0.f;
      const u16x8 h00 = *reinterpret_cast<const u16x8*>(hb0 + (size_t)sj0 * DOUT);
      const u16x8 h01 = *reinterpret_cast<const u16x8*>(hb1 + (size_t)sj0 * DOUT);
      const u16x8 h10 = *reinterpret_cast<const u16x8*>(hb0 + (size_t)sj1 * DOUT);
      const u16x8 h11 = *reinterpret_cast<const u16x8*>(hb1 + (size_t)sj1 * DOUT);
      #pragma unroll
      for (int k = 0; k < 8; ++k) {
        acc[k]     = fmaf(a0, b2f((unsigned short)h00[k]), acc[k]);
        acc[k + 8] = fmaf(a0, b2f((unsigned short)h01[k]), acc[k + 8]);
      }
      #pragma unroll
      for (int k = 0; k < 8; ++k) {
        acc[k]     = fmaf(a1, b2f((unsigned short)h10[k]), acc[k]);
        acc[k + 8] = fmaf(a1, b2f((unsigned short)h11[k]), acc[k + 8]);
      }
    }
  }

  #pragma unroll
  for (int k = 0; k < 16; ++k) {
    acc[k] += __shfl_xor(acc[k], 16);
    acc[k] += __shfl_xor(acc[k], 32);
  }

  if (lane < 16) {
    const float inv = 1.f / (s + 1e-16f);
    const int cb = c16 * 8;
    float o[16];
    #pragma unroll
    for (int k = 0; k < 8; ++k) {
      o[k]     = fmaxf(acc[k] * inv + bias[cb + k], 0.f);
      o[k + 8] = fmaxf(acc[k + 8] * inv + bias[128 + cb + k], 0.f);
    }
    if (MODE == 1) {
      #pragma unroll
      for (int k = 0; k < 8; ++k) {
        o[k]     += base[(size_t)n * DOUT + cb + k];
        o[k + 8] += base[(size_t)n * DOUT + 128 + cb + k];
      }
    }
    *reinterpret_cast<float4*>(out + (size_t)n * DOUT + cb)           = make_float4(o[0], o[1], o[2], o[3]);
    *reinterpret_cast<float4*>(out + (size_t)n * DOUT + cb + 4)       = make_float4(o[4], o[5], o[6], o[7]);
    *reinterpret_cast<float4*>(out + (size_t)n * DOUT + 128 + cb)     = make_float4(o[8], o[9], o[10], o[11]);
    *reinterpret_cast<float4*>(out + (size_t)n * DOUT + 128 + cb + 4) = make_float4(o[12], o[13], o[14], o[15]);
    u16x8 ob0, ob1;
    #pragma unroll
    for (int k = 0; k < 8; ++k) { ob0[k] = f2b(o[k]); ob1[k] = f2b(o[k + 8]); }
    *reinterpret_cast<u16x8*>(outb + (size_t)n * DOUT + cb)       = ob0;
    *reinterpret_cast<u16x8*>(outb + (size_t)n * DOUT + 128 + cb) = ob1;
  }
}

// ---------------- launch ----------------
extern "C" void kernel_launch(void* const* d_in, const int* in_sizes, int n_in,
                              void* d_out, int out_size, void* d_ws, size_t ws_size,
                              hipStream_t stream) {
  const float* x   = (const float*)d_in[0];
  const int*   ei  = (const int*)d_in[1];
  const float* W1  = (const float*)d_in[2];
  const float* as1 = (const float*)d_in[3];
  const float* ad1 = (const float*)d_in[4];
  const float* b1  = (const float*)d_in[5];
  const float* W2  = (const float*)d_in[6];
  const float* as2 = (const float*)d_in[7];
  const float* ad2 = (const float*)d_in[8];
  const float* b2  = (const float*)d_in[9];
  const float* W3  = (const float*)d_in[10];
  const float* as3 = (const float*)d_in[11];
  const float* ad3 = (const float*)d_in[12];
  const float* b3  = (const float*)d_in[13];
  float* out = (float*)d_out;   // doubles as fp32 layer output

  char* ws = (char*)d_ws;
  size_t off = 0;
  auto alloc = [&](size_t bytes) -> void* {
    void* p = ws + off;
    off = (off + bytes + 255) & ~(size_t)255;
    return p;
  };
  unsigned short* Xb   = (unsigned short*)alloc((size_t)NNODES * 512 * sizeof(unsigned short));
  unsigned short* Hb   = (unsigned short*)alloc((size_t)NNODES * DOUT * sizeof(unsigned short));
  unsigned short* W1t  = (unsigned short*)alloc((size_t)512 * DOUT * sizeof(unsigned short));
  unsigned short* W2t  = (unsigned short*)alloc((size_t)DOUT * DOUT * sizeof(unsigned short));
  unsigned short* W3t  = (unsigned short*)alloc((size_t)DOUT * DOUT * sizeof(unsigned short));
  float* asn  = (float*)alloc(NNODES * sizeof(float));
  float* adn  = (float*)alloc(NNODES * sizeof(float));
  int*   deg  = (int*)alloc(NNODES * sizeof(int));
  int*   rowptr = (int*)alloc((NNODES + 1) * sizeof(int));
  int*   bsum = (int*)alloc(SCANB * sizeof(int));
  int*   bexcl = (int*)alloc(SCANB * sizeof(int));
  int*   bcnt = (int*)alloc(NB * sizeof(int));
  int*   esrc = (int*)alloc((size_t)(NEDGES + NNODES) * sizeof(int));
  int2*  bbuf = (int2*)alloc((size_t)NB * BCAP * sizeof(int2));

  const int EP = NEDGES + NNODES;
  hipMemsetAsync(deg, 0, NNODES * sizeof(int), stream);
  hipMemsetAsync(bcnt, 0, NB * sizeof(int), stream);

  // CSR build: bucket (LDS-hist, hist fused) -> scan -> unbucket
  k_bucket<<<(EP + CHUNK - 1) / CHUNK, 256, 0, stream>>>(ei, deg, bcnt, bbuf);
  k_scan1<<<SCANB, 256, 0, stream>>>(deg, rowptr, bsum);
  k_scan2<<<1, 256, 0, stream>>>(bsum, bexcl);
  k_scan3<<<SCANB, 256, 0, stream>>>(rowptr, bexcl);
  k_unbucket<<<NB, 256, 0, stream>>>(bbuf, bcnt, rowptr, esrc);

  // casts
  k_castX<<<2048, 256, 0, stream>>>((const float4*)x, (ushort4*)Xb, NNODES * 512 / 4);
  k_castW<512><<<(512 * DOUT + 255) / 256, 256, 0, stream>>>(W1, W1t);
  k_castW<256><<<(256 * DOUT + 255) / 256, 256, 0, stream>>>(W2, W2t);
  k_castW<256><<<(256 * DOUT + 255) / 256, 256, 0, stream>>>(W3, W3t);

  const int gemmGrid = (NNODES + 63) / 64;
  const int aggGrid  = (NNODES + 3) / 4;

  // layer 1
  k_gemm_mfma<512><<<gemmGrid, 256, 0, stream>>>(Xb, W1t, as1, ad1, Hb, asn, adn);
  k_agg<0><<<aggGrid, 256, 0, stream>>>(Hb, rowptr, esrc, asn, adn, b1, nullptr, out, Xb);
  // layer 2 (Xb now holds bf16 of layer-1 output)
  k_gemm_mfma<256><<<gemmGrid, 256, 0, stream>>>(Xb, W2t, as2, ad2, Hb, asn, adn);
  k_agg<1><<<aggGrid, 256, 0, stream>>>(Hb, rowptr, esrc, asn, adn, b2, out, out, Xb);
  // layer 3
  k_gemm_mfma<256><<<gemmGrid, 256, 0, stream>>>(Xb, W3t, as3, ad3, Hb, asn, adn);
  k_agg<1><<<aggGrid, 256, 0, stream>>>(Hb, rowptr, esrc, asn, adn, b3, out, out, Xb);
}

// Round 10
// 598.432 us; speedup vs baseline: 2.6679x; 1.0856x over previous
//
#include <hip/hip_runtime.h>
#include <math.h>

#define NNODES 50000
#define NEDGES 1600000
#define DOUT 256
#define NEG_SLOPE 0.2f
#define SCANB ((NNODES + 255) / 256)
#define NB ((NNODES + 255) / 256)   // dst buckets of 256 nodes (196)
#define BCAP 10240                  // bucket capacity (mean ~8420, >15 sigma margin)
#define CHUNK 8192                  // edges per bucket block
#define BBUCKET ((NEDGES + NNODES + CHUNK - 1) / CHUNK)   // 202
#define BCASTX 2048
#define GEMM_GRID ((NNODES + 63) / 64)                    // 782

typedef __attribute__((ext_vector_type(8))) short short8;
typedef __attribute__((ext_vector_type(8))) unsigned short u16x8;
typedef __attribute__((ext_vector_type(4))) float f32x4;

__device__ __forceinline__ float lrelu(float e) { return e > 0.f ? e : NEG_SLOPE * e; }
__device__ __forceinline__ float b2f(unsigned short u) {
  union { unsigned u; float f; } c; c.u = ((unsigned)u) << 16; return c.f;
}
__device__ __forceinline__ unsigned short f2b(float f) {
  union { float f; unsigned u; } c; c.f = f;
  return (unsigned short)((c.u + 0x7fffu + ((c.u >> 16) & 1u)) >> 16);
}

// ---------------- fat pre kernel: bucket || castX || castW1-3 ----------------
__device__ void castW_body(int bid, int DIN, const float* __restrict__ W,
                           unsigned short* __restrict__ Wt) {
  const int idx = bid * 256 + threadIdx.x;
  if (idx >= DIN * DOUT) return;
  const int k = idx / DOUT, n = idx % DOUT;
  Wt[n * DIN + k] = f2b(W[idx]);
}

__global__ __launch_bounds__(256) void k_pre(
    const int* __restrict__ ei, int* __restrict__ deg, int* __restrict__ bcnt,
    int2* __restrict__ bbuf, const float4* __restrict__ x4, ushort4* __restrict__ xb4,
    const float* __restrict__ W1, unsigned short* __restrict__ W1t,
    const float* __restrict__ W2, unsigned short* __restrict__ W2t,
    const float* __restrict__ W3, unsigned short* __restrict__ W3t)
{
  __shared__ int hcnt[NB];
  __shared__ int lpos[NB];
  int b = blockIdx.x;
  const int t = threadIdx.x;

  if (b < BBUCKET) {
    // bucket: per-block LDS histogram -> one reserve atomic per (block,bucket)
    // -> block-private contiguous sub-segment writes (L2-merged lines).
    const int e0 = b * CHUNK;
    const int EP = NEDGES + NNODES;
    const int ecnt = min(CHUNK, EP - e0);
    for (int i = t; i < NB; i += 256) hcnt[i] = 0;
    __syncthreads();
    for (int i = t; i < ecnt; i += 256) {
      const int e = e0 + i;
      int dst = (e < NEDGES) ? ei[NEDGES + e] : (e - NEDGES);
      atomicAdd(&deg[dst], 1);
      atomicAdd(&hcnt[dst >> 8], 1);
    }
    __syncthreads();
    for (int bb = t; bb < NB; bb += 256) {
      const int c = hcnt[bb];
      lpos[bb] = (c > 0) ? atomicAdd(&bcnt[bb], c) : 0;
    }
    __syncthreads();
    for (int i = t; i < ecnt; i += 256) {
      const int e = e0 + i;
      int src, dst;
      if (e < NEDGES) { src = ei[e]; dst = ei[NEDGES + e]; }
      else            { src = e - NEDGES; dst = src; }
      const int bb = dst >> 8;
      const int p = atomicAdd(&lpos[bb], 1);
      bbuf[(size_t)bb * BCAP + p] = make_int2(src, dst);
    }
    return;
  }
  b -= BBUCKET;
  if (b < BCASTX) {
    const int n4 = NNODES * 512 / 4;
    for (int i = b * 256 + t; i < n4; i += BCASTX * 256) {
      float4 v = x4[i];
      ushort4 o;
      o.x = f2b(v.x); o.y = f2b(v.y); o.z = f2b(v.z); o.w = f2b(v.w);
      xb4[i] = o;
    }
    return;
  }
  b -= BCASTX;
  if (b < 512) { castW_body(b, 512, W1, W1t); return; }
  b -= 512;
  if (b < 256) { castW_body(b, 256, W2, W2t); return; }
  b -= 256;
  castW_body(b, 256, W3, W3t);
}

// ---------------- scans ----------------
__global__ __launch_bounds__(256) void k_scan1(const int* __restrict__ deg,
                                               int* __restrict__ rowptr,
                                               int* __restrict__ bsum) {
  __shared__ int wsum[4];
  const int t = threadIdx.x, lane = t & 63, w = t >> 6;
  const int i = blockIdx.x * 256 + t;
  int x = (i < NNODES) ? deg[i] : 0;
  #pragma unroll
  for (int off = 1; off < 64; off <<= 1) {
    int y = __shfl_up(x, off);
    if (lane >= off) x += y;
  }
  if (lane == 63) wsum[w] = x;
  __syncthreads();
  int s0 = wsum[0], s1 = wsum[1], s2 = wsum[2], s3 = wsum[3];
  int woff = (w > 0 ? s0 : 0) + (w > 1 ? s1 : 0) + (w > 2 ? s2 : 0);
  if (i < NNODES) rowptr[i + 1] = woff + x;
  if (t == 255) bsum[blockIdx.x] = woff + x;
}

__global__ __launch_bounds__(256) void k_scan2(int* __restrict__ bsum,
                                               int* __restrict__ bexcl) {
  __shared__ int wsum[4];
  const int t = threadIdx.x, lane = t & 63, w = t >> 6;
  int v = (t < SCANB) ? bsum[t] : 0;
  int x = v;
  #pragma unroll
  for (int off = 1; off < 64; off <<= 1) {
    int y = __shfl_up(x, off);
    if (lane >= off) x += y;
  }
  if (lane == 63) wsum[w] = x;
  __syncthreads();
  int s0 = wsum[0], s1 = wsum[1], s2 = wsum[2], s3 = wsum[3];
  int woff = (w > 0 ? s0 : 0) + (w > 1 ? s1 : 0) + (w > 2 ? s2 : 0);
  if (t < SCANB) bexcl[t] = woff + x - v;
}

__global__ __launch_bounds__(256) void k_scan3(int* __restrict__ rowptr,
                                               const int* __restrict__ bexcl) {
  const int i = blockIdx.x * 256 + threadIdx.x;
  if (i == 0) rowptr[0] = 0;
  if (i < NNODES) rowptr[i + 1] += bexcl[blockIdx.x];
}

// ---------------- GEMM body (device) ----------------
template<int DIN>
__device__ void gemm_body(int bid,
    const unsigned short* __restrict__ Ab, const unsigned short* __restrict__ Wt,
    const float* __restrict__ a_src, const float* __restrict__ a_dst,
    unsigned short* __restrict__ Hb, float* __restrict__ asn, float* __restrict__ adn,
    float (*s_ps)[64], float (*s_pd)[64])
{
  const int lane = threadIdx.x & 63;
  const int wv = threadIdx.x >> 6;
  const int row0 = bid * 64;
  const int col0 = wv * 64;
  const int lr = lane & 15;
  const int lk = lane >> 4;

  f32x4 acc[4][4];
  #pragma unroll
  for (int m = 0; m < 4; ++m)
    #pragma unroll
    for (int n = 0; n < 4; ++n)
      acc[m][n] = (f32x4){0.f, 0.f, 0.f, 0.f};

  const unsigned short* arow[4];
  #pragma unroll
  for (int m = 0; m < 4; ++m) {
    int r = row0 + m * 16 + lr;
    if (r > NNODES - 1) r = NNODES - 1;
    arow[m] = Ab + (size_t)r * DIN + lk * 8;
  }
  const unsigned short* brow[4];
  #pragma unroll
  for (int n = 0; n < 4; ++n)
    brow[n] = Wt + (size_t)(col0 + n * 16 + lr) * DIN + lk * 8;

  for (int k = 0; k < DIN; k += 32) {
    short8 aF[4], bF[4];
    #pragma unroll
    for (int m = 0; m < 4; ++m)
      aF[m] = *reinterpret_cast<const short8*>(arow[m] + k);
    #pragma unroll
    for (int n = 0; n < 4; ++n)
      bF[n] = *reinterpret_cast<const short8*>(brow[n] + k);
    #pragma unroll
    for (int m = 0; m < 4; ++m)
      #pragma unroll
      for (int n = 0; n < 4; ++n)
        acc[m][n] = __builtin_amdgcn_mfma_f32_16x16x32_bf16(aF[m], bF[n], acc[m][n], 0, 0, 0);
  }

  float asv[4], adv[4];
  #pragma unroll
  for (int n = 0; n < 4; ++n) {
    int c = col0 + n * 16 + lr;
    asv[n] = a_src[c];
    adv[n] = a_dst[c];
  }

  #pragma unroll
  for (int m = 0; m < 4; ++m) {
    float ps[4] = {0.f, 0.f, 0.f, 0.f};
    float pd[4] = {0.f, 0.f, 0.f, 0.f};
    #pragma unroll
    for (int n = 0; n < 4; ++n) {
      int col = col0 + n * 16 + lr;
      #pragma unroll
      for (int j = 0; j < 4; ++j) {
        int row = row0 + m * 16 + lk * 4 + j;
        float v = acc[m][n][j];
        if (row < NNODES)
          Hb[(size_t)row * DOUT + col] = f2b(v);
        ps[j] = fmaf(v, asv[n], ps[j]);
        pd[j] = fmaf(v, adv[n], pd[j]);
      }
    }
    #pragma unroll
    for (int off = 1; off < 16; off <<= 1) {
      #pragma unroll
      for (int j = 0; j < 4; ++j) {
        ps[j] += __shfl_xor(ps[j], off);
        pd[j] += __shfl_xor(pd[j], off);
      }
    }
    if (lr == 0) {
      #pragma unroll
      for (int j = 0; j < 4; ++j) {
        s_ps[wv][m * 16 + lk * 4 + j] = ps[j];
        s_pd[wv][m * 16 + lk * 4 + j] = pd[j];
      }
    }
  }

  __syncthreads();
  const int t = threadIdx.x;
  if (t < 64) {
    int row = row0 + t;
    if (row < NNODES) {
      asn[row] = s_ps[0][t] + s_ps[1][t] + s_ps[2][t] + s_ps[3][t];
      adn[row] = s_pd[0][t] + s_pd[1][t] + s_pd[2][t] + s_pd[3][t];
    }
  }
}

// standalone gemm (layers 2,3)
template<int DIN>
__global__ __launch_bounds__(256) void k_gemm_mfma(
    const unsigned short* __restrict__ Ab, const unsigned short* __restrict__ Wt,
    const float* __restrict__ a_src, const float* __restrict__ a_dst,
    unsigned short* __restrict__ Hb, float* __restrict__ asn, float* __restrict__ adn)
{
  __shared__ float s_ps[4][64];
  __shared__ float s_pd[4][64];
  gemm_body<DIN>(blockIdx.x, Ab, Wt, a_src, a_dst, Hb, asn, adn, s_ps, s_pd);
}

// ---------------- fat mid kernel: unbucket || gemm1 ----------------
__global__ __launch_bounds__(256) void k_mid(
    const int2* __restrict__ bbuf, const int* __restrict__ bcnt,
    const int* __restrict__ rowptr, int* __restrict__ esrc,
    const unsigned short* __restrict__ Xb, const unsigned short* __restrict__ W1t,
    const float* __restrict__ a_src, const float* __restrict__ a_dst,
    unsigned short* __restrict__ Hb, float* __restrict__ asn, float* __restrict__ adn)
{
  __shared__ float s_ps[4][64];
  __shared__ float s_pd[4][64];
  __shared__ int fill[256];
  if (blockIdx.x < NB) {
    // unbucket: contiguous esrc region per block -> L2-merged writes
    const int b = blockIdx.x;
    fill[threadIdx.x] = 0;
    __syncthreads();
    const int cnt = bcnt[b];
    const int2* __restrict__ bp = bbuf + (size_t)b * BCAP;
    for (int i = threadIdx.x; i < cnt; i += 256) {
      const int2 sd = bp[i];
      const int pos = rowptr[sd.y] + atomicAdd(&fill[sd.y & 255], 1);
      esrc[pos] = sd.x;
    }
    return;
  }
  gemm_body<512>(blockIdx.x - NB, Xb, W1t, a_src, a_dst, Hb, asn, adn, s_ps, s_pd);
}

// ---------------- attention softmax + aggregation (single sweep) ----------------
// WXB=0 skips the bf16 mirror write (layer 3: nothing consumes it).
template<int MODE, int WXB>
__global__ __launch_bounds__(256) void k_agg(
    const unsigned short* __restrict__ Hb, const int* __restrict__ rowptr,
    const int* __restrict__ esrc, const float* __restrict__ asn,
    const float* __restrict__ adn, const float* __restrict__ bias,
    const float* __restrict__ base, float* __restrict__ out,
    unsigned short* __restrict__ outb)
{
  const int lane = threadIdx.x & 63;
  const int wv = threadIdx.x >> 6;
  const int n = blockIdx.x * 4 + wv;
  if (n >= NNODES) return;
  const int start = rowptr[n];
  const int end = rowptr[n + 1];
  const float adv = adn[n];

  const int q = lane >> 4;
  const int c16 = lane & 15;
  const unsigned short* __restrict__ hb0 = Hb + c16 * 8;
  const unsigned short* __restrict__ hb1 = Hb + 128 + c16 * 8;

  float m = -1e30f, s = 0.f;
  float acc[16];
  #pragma unroll
  for (int k = 0; k < 16; ++k) acc[k] = 0.f;

  for (int c0 = start; c0 < end; c0 += 64) {
    const int i = c0 + lane;
    int msrc = 0;
    float e = -1e30f;
    if (i < end) {
      msrc = esrc[i];
      e = lrelu(asn[msrc] + adv);
    }
    float cm = e;
    #pragma unroll
    for (int off = 32; off > 0; off >>= 1) cm = fmaxf(cm, __shfl_xor(cm, off));
    const float mn = fmaxf(m, cm);
    const float resc = __expf(m - mn);
    s *= resc;
    #pragma unroll
    for (int k = 0; k < 16; ++k) acc[k] *= resc;
    m = mn;
    float p = __expf(e - mn);
    float cs = p;
    #pragma unroll
    for (int off = 32; off > 0; off >>= 1) cs += __shfl_xor(cs, off);
    s += cs;

    const int cnt = min(64, end - c0);
    const int qcnt = (cnt + 3) >> 2;
    for (int jj = 0; jj < qcnt; jj += 2) {
      const int e0 = 4 * jj + q;
      const int e1 = e0 + 4;
      const int s0 = (e0 < cnt) ? e0 : 0;
      const int s1 = (e1 < cnt) ? e1 : 0;
      float a0 = __shfl(p, s0);
      const int sj0 = __shfl(msrc, s0);
      float a1 = __shfl(p, s1);
      const int sj1 = __shfl(msrc, s1);
      if (e0 >= cnt) a0 = 0.f;
      if (jj + 1 >= qcnt || e1 >= cnt) a1 = 0.f;
      if (a0 != 0.f) {   // also skips underflow-zero weights: contribution is 0
        const u16x8 h00 = *reinterpret_cast<const u16x8*>(hb0 + (size_t)sj0 * DOUT);
        const u16x8 h01 = *reinterpret_cast<const u16x8*>(hb1 + (size_t)sj0 * DOUT);
        #pragma unroll
        for (int k = 0; k < 8; ++k) {
          acc[k]     = fmaf(a0, b2f((unsigned short)h00[k]), acc[k]);
          acc[k + 8] = fmaf(a0, b2f((unsigned short)h01[k]), acc[k + 8]);
        }
      }
      if (a1 != 0.f) {
        const u16x8 h10 = *reinterpret_cast<const u16x8*>(hb0 + (size_t)sj1 * DOUT);
        const u16x8 h11 = *reinterpret_cast<const u16x8*>(hb1 + (size_t)sj1 * DOUT);
        #pragma unroll
        for (int k = 0; k < 8; ++k) {
          acc[k]     = fmaf(a1, b2f((unsigned short)h10[k]), acc[k]);
          acc[k + 8] = fmaf(a1, b2f((unsigned short)h11[k]), acc[k + 8]);
        }
      }
    }
  }

  #pragma unroll
  for (int k = 0; k < 16; ++k) {
    acc[k] += __shfl_xor(acc[k], 16);
    acc[k] += __shfl_xor(acc[k], 32);
  }

  if (lane < 16) {
    const float inv = 1.f / (s + 1e-16f);
    const int cb = c16 * 8;
    float o[16];
    #pragma unroll
    for (int k = 0; k < 8; ++k) {
      o[k]     = fmaxf(acc[k] * inv + bias[cb + k], 0.f);
      o[k + 8] = fmaxf(acc[k + 8] * inv + bias[128 + cb + k], 0.f);
    }
    if (MODE == 1) {
      #pragma unroll
      for (int k = 0; k < 8; ++k) {
        o[k]     += base[(size_t)n * DOUT + cb + k];
        o[k + 8] += base[(size_t)n * DOUT + 128 + cb + k];
      }
    }
    *reinterpret_cast<float4*>(out + (size_t)n * DOUT + cb)           = make_float4(o[0], o[1], o[2], o[3]);
    *reinterpret_cast<float4*>(out + (size_t)n * DOUT + cb + 4)       = make_float4(o[4], o[5], o[6], o[7]);
    *reinterpret_cast<float4*>(out + (size_t)n * DOUT + 128 + cb)     = make_float4(o[8], o[9], o[10], o[11]);
    *reinterpret_cast<float4*>(out + (size_t)n * DOUT + 128 + cb + 4) = make_float4(o[12], o[13], o[14], o[15]);
    if (WXB) {
      u16x8 ob0, ob1;
      #pragma unroll
      for (int k = 0; k < 8; ++k) { ob0[k] = f2b(o[k]); ob1[k] = f2b(o[k + 8]); }
      *reinterpret_cast<u16x8*>(outb + (size_t)n * DOUT + cb)       = ob0;
      *reinterpret_cast<u16x8*>(outb + (size_t)n * DOUT + 128 + cb) = ob1;
    }
  }
}

// ---------------- launch ----------------
extern "C" void kernel_launch(void* const* d_in, const int* in_sizes, int n_in,
                              void* d_out, int out_size, void* d_ws, size_t ws_size,
                              hipStream_t stream) {
  const float* x   = (const float*)d_in[0];
  const int*   ei  = (const int*)d_in[1];
  const float* W1  = (const float*)d_in[2];
  const float* as1 = (const float*)d_in[3];
  const float* ad1 = (const float*)d_in[4];
  const float* b1  = (const float*)d_in[5];
  const float* W2  = (const float*)d_in[6];
  const float* as2 = (const float*)d_in[7];
  const float* ad2 = (const float*)d_in[8];
  const float* b2  = (const float*)d_in[9];
  const float* W3  = (const float*)d_in[10];
  const float* as3 = (const float*)d_in[11];
  const float* ad3 = (const float*)d_in[12];
  const float* b3  = (const float*)d_in[13];
  float* out = (float*)d_out;   // doubles as fp32 layer output

  char* ws = (char*)d_ws;
  size_t off = 0;
  auto alloc = [&](size_t bytes) -> void* {
    void* p = ws + off;
    off = (off + bytes + 255) & ~(size_t)255;
    return p;
  };
  unsigned short* Xb   = (unsigned short*)alloc((size_t)NNODES * 512 * sizeof(unsigned short));
  unsigned short* Hb   = (unsigned short*)alloc((size_t)NNODES * DOUT * sizeof(unsigned short));
  unsigned short* W1t  = (unsigned short*)alloc((size_t)512 * DOUT * sizeof(unsigned short));
  unsigned short* W2t  = (unsigned short*)alloc((size_t)DOUT * DOUT * sizeof(unsigned short));
  unsigned short* W3t  = (unsigned short*)alloc((size_t)DOUT * DOUT * sizeof(unsigned short));
  float* asn  = (float*)alloc(NNODES * sizeof(float));
  float* adn  = (float*)alloc(NNODES * sizeof(float));
  int*   deg  = (int*)alloc(NNODES * sizeof(int));
  int*   rowptr = (int*)alloc((NNODES + 1) * sizeof(int));
  int*   bsum = (int*)alloc(SCANB * sizeof(int));
  int*   bexcl = (int*)alloc(SCANB * sizeof(int));
  int*   bcnt = (int*)alloc(NB * sizeof(int));
  int*   esrc = (int*)alloc((size_t)(NEDGES + NNODES) * sizeof(int));
  int2*  bbuf = (int2*)alloc((size_t)NB * BCAP * sizeof(int2));

  hipMemsetAsync(deg, 0, NNODES * sizeof(int), stream);
  hipMemsetAsync(bcnt, 0, NB * sizeof(int), stream);

  // fat pre: bucket || castX || castW1-3
  const int preGrid = BBUCKET + BCASTX + 512 + 256 + 256;
  k_pre<<<preGrid, 256, 0, stream>>>(ei, deg, bcnt, bbuf,
                                     (const float4*)x, (ushort4*)Xb,
                                     W1, W1t, W2, W2t, W3, W3t);
  k_scan1<<<SCANB, 256, 0, stream>>>(deg, rowptr, bsum);
  k_scan2<<<1, 256, 0, stream>>>(bsum, bexcl);
  k_scan3<<<SCANB, 256, 0, stream>>>(rowptr, bexcl);

  // fat mid: unbucket || gemm layer 1
  k_mid<<<NB + GEMM_GRID, 256, 0, stream>>>(bbuf, bcnt, rowptr, esrc,
                                            Xb, W1t, as1, ad1, Hb, asn, adn);

  const int aggGrid = (NNODES + 3) / 4;

  // layer 1
  k_agg<0, 1><<<aggGrid, 256, 0, stream>>>(Hb, rowptr, esrc, asn, adn, b1, nullptr, out, Xb);
  // layer 2 (Xb holds bf16 of layer-1 output)
  k_gemm_mfma<256><<<GEMM_GRID, 256, 0, stream>>>(Xb, W2t, as2, ad2, Hb, asn, adn);
  k_agg<1, 1><<<aggGrid, 256, 0, stream>>>(Hb, rowptr, esrc, asn, adn, b2, out, out, Xb);
  // layer 3 (no bf16 mirror needed)
  k_gemm_mfma<256><<<GEMM_GRID, 256, 0, stream>>>(Xb, W3t, as3, ad3, Hb, asn, adn);
  k_agg<1, 0><<<aggGrid, 256, 0, stream>>>(Hb, rowptr, esrc, asn, adn, b3, out, out, Xb);
}

// Round 11
// 595.424 us; speedup vs baseline: 2.6813x; 1.0051x over previous
//
#include <hip/hip_runtime.h>
#include <math.h>

#define NNODES 50000
#define NEDGES 1600000
#define DOUT 256
#define NEG_SLOPE 0.2f
#define SCANB ((NNODES + 255) / 256)
#define NB ((NNODES + 255) / 256)   // dst buckets of 256 nodes (196)
#define BCAP 10240                  // bucket capacity (mean ~8420, >15 sigma margin)
#define CHUNK 8192                  // edges per bucket block
#define BBUCKET ((NEDGES + NNODES + CHUNK - 1) / CHUNK)   // 202
#define BCASTX 2048
#define GEMM_GRID ((NNODES + 63) / 64)                    // 782
#define CHKSH 13                    // src-chunk = src >> 13 (8192 rows = 4MB of Hb)
#define NCHK ((NNODES + (1 << CHKSH) - 1) >> CHKSH)       // 7

typedef __attribute__((ext_vector_type(8))) short short8;
typedef __attribute__((ext_vector_type(8))) unsigned short u16x8;
typedef __attribute__((ext_vector_type(4))) float f32x4;

__device__ __forceinline__ float lrelu(float e) { return e > 0.f ? e : NEG_SLOPE * e; }
__device__ __forceinline__ float b2f(unsigned short u) {
  union { unsigned u; float f; } c; c.u = ((unsigned)u) << 16; return c.f;
}
__device__ __forceinline__ unsigned short f2b(float f) {
  union { float f; unsigned u; } c; c.f = f;
  return (unsigned short)((c.u + 0x7fffu + ((c.u >> 16) & 1u)) >> 16);
}

// ---------------- fat pre kernel: bucket || castX || castW1-3 ----------------
__device__ void castW_body(int bid, int DIN, const float* __restrict__ W,
                           unsigned short* __restrict__ Wt) {
  const int idx = bid * 256 + threadIdx.x;
  if (idx >= DIN * DOUT) return;
  const int k = idx / DOUT, n = idx % DOUT;
  Wt[n * DIN + k] = f2b(W[idx]);
}

__global__ __launch_bounds__(256) void k_pre(
    const int* __restrict__ ei, int* __restrict__ deg, int* __restrict__ bcnt,
    int2* __restrict__ bbuf, const float4* __restrict__ x4, ushort4* __restrict__ xb4,
    const float* __restrict__ W1, unsigned short* __restrict__ W1t,
    const float* __restrict__ W2, unsigned short* __restrict__ W2t,
    const float* __restrict__ W3, unsigned short* __restrict__ W3t)
{
  __shared__ int hcnt[NB];
  __shared__ int lpos[NB];
  int b = blockIdx.x;
  const int t = threadIdx.x;

  if (b < BBUCKET) {
    // bucket: per-block LDS histogram -> one reserve atomic per (block,bucket)
    // -> block-private contiguous sub-segment writes (L2-merged lines).
    const int e0 = b * CHUNK;
    const int EP = NEDGES + NNODES;
    const int ecnt = min(CHUNK, EP - e0);
    for (int i = t; i < NB; i += 256) hcnt[i] = 0;
    __syncthreads();
    for (int i = t; i < ecnt; i += 256) {
      const int e = e0 + i;
      int dst = (e < NEDGES) ? ei[NEDGES + e] : (e - NEDGES);
      atomicAdd(&deg[dst], 1);
      atomicAdd(&hcnt[dst >> 8], 1);
    }
    __syncthreads();
    for (int bb = t; bb < NB; bb += 256) {
      const int c = hcnt[bb];
      lpos[bb] = (c > 0) ? atomicAdd(&bcnt[bb], c) : 0;
    }
    __syncthreads();
    for (int i = t; i < ecnt; i += 256) {
      const int e = e0 + i;
      int src, dst;
      if (e < NEDGES) { src = ei[e]; dst = ei[NEDGES + e]; }
      else            { src = e - NEDGES; dst = src; }
      const int bb = dst >> 8;
      const int p = atomicAdd(&lpos[bb], 1);
      bbuf[(size_t)bb * BCAP + p] = make_int2(src, dst);
    }
    return;
  }
  b -= BBUCKET;
  if (b < BCASTX) {
    const int n4 = NNODES * 512 / 4;
    for (int i = b * 256 + t; i < n4; i += BCASTX * 256) {
      float4 v = x4[i];
      ushort4 o;
      o.x = f2b(v.x); o.y = f2b(v.y); o.z = f2b(v.z); o.w = f2b(v.w);
      xb4[i] = o;
    }
    return;
  }
  b -= BCASTX;
  if (b < 512) { castW_body(b, 512, W1, W1t); return; }
  b -= 512;
  if (b < 256) { castW_body(b, 256, W2, W2t); return; }
  b -= 256;
  castW_body(b, 256, W3, W3t);
}

// ---------------- scans ----------------
__global__ __launch_bounds__(256) void k_scan1(const int* __restrict__ deg,
                                               int* __restrict__ rowptr,
                                               int* __restrict__ bsum) {
  __shared__ int wsum[4];
  const int t = threadIdx.x, lane = t & 63, w = t >> 6;
  const int i = blockIdx.x * 256 + t;
  int x = (i < NNODES) ? deg[i] : 0;
  #pragma unroll
  for (int off = 1; off < 64; off <<= 1) {
    int y = __shfl_up(x, off);
    if (lane >= off) x += y;
  }
  if (lane == 63) wsum[w] = x;
  __syncthreads();
  int s0 = wsum[0], s1 = wsum[1], s2 = wsum[2], s3 = wsum[3];
  int woff = (w > 0 ? s0 : 0) + (w > 1 ? s1 : 0) + (w > 2 ? s2 : 0);
  if (i < NNODES) rowptr[i + 1] = woff + x;
  if (t == 255) bsum[blockIdx.x] = woff + x;
}

__global__ __launch_bounds__(256) void k_scan2(int* __restrict__ bsum,
                                               int* __restrict__ bexcl) {
  __shared__ int wsum[4];
  const int t = threadIdx.x, lane = t & 63, w = t >> 6;
  int v = (t < SCANB) ? bsum[t] : 0;
  int x = v;
  #pragma unroll
  for (int off = 1; off < 64; off <<= 1) {
    int y = __shfl_up(x, off);
    if (lane >= off) x += y;
  }
  if (lane == 63) wsum[w] = x;
  __syncthreads();
  int s0 = wsum[0], s1 = wsum[1], s2 = wsum[2], s3 = wsum[3];
  int woff = (w > 0 ? s0 : 0) + (w > 1 ? s1 : 0) + (w > 2 ? s2 : 0);
  if (t < SCANB) bexcl[t] = woff + x - v;
}

__global__ __launch_bounds__(256) void k_scan3(int* __restrict__ rowptr,
                                               const int* __restrict__ bexcl) {
  const int i = blockIdx.x * 256 + threadIdx.x;
  if (i == 0) rowptr[0] = 0;
  if (i < NNODES) rowptr[i + 1] += bexcl[blockIdx.x];
}

// ---------------- GEMM body (device) ----------------
template<int DIN>
__device__ void gemm_body(int bid,
    const unsigned short* __restrict__ Ab, const unsigned short* __restrict__ Wt,
    const float* __restrict__ a_src, const float* __restrict__ a_dst,
    unsigned short* __restrict__ Hb, float* __restrict__ asn, float* __restrict__ adn,
    float (*s_ps)[64], float (*s_pd)[64])
{
  const int lane = threadIdx.x & 63;
  const int wv = threadIdx.x >> 6;
  const int row0 = bid * 64;
  const int col0 = wv * 64;
  const int lr = lane & 15;
  const int lk = lane >> 4;

  f32x4 acc[4][4];
  #pragma unroll
  for (int m = 0; m < 4; ++m)
    #pragma unroll
    for (int n = 0; n < 4; ++n)
      acc[m][n] = (f32x4){0.f, 0.f, 0.f, 0.f};

  const unsigned short* arow[4];
  #pragma unroll
  for (int m = 0; m < 4; ++m) {
    int r = row0 + m * 16 + lr;
    if (r > NNODES - 1) r = NNODES - 1;
    arow[m] = Ab + (size_t)r * DIN + lk * 8;
  }
  const unsigned short* brow[4];
  #pragma unroll
  for (int n = 0; n < 4; ++n)
    brow[n] = Wt + (size_t)(col0 + n * 16 + lr) * DIN + lk * 8;

  for (int k = 0; k < DIN; k += 32) {
    short8 aF[4], bF[4];
    #pragma unroll
    for (int m = 0; m < 4; ++m)
      aF[m] = *reinterpret_cast<const short8*>(arow[m] + k);
    #pragma unroll
    for (int n = 0; n < 4; ++n)
      bF[n] = *reinterpret_cast<const short8*>(brow[n] + k);
    #pragma unroll
    for (int m = 0; m < 4; ++m)
      #pragma unroll
      for (int n = 0; n < 4; ++n)
        acc[m][n] = __builtin_amdgcn_mfma_f32_16x16x32_bf16(aF[m], bF[n], acc[m][n], 0, 0, 0);
  }

  float asv[4], adv[4];
  #pragma unroll
  for (int n = 0; n < 4; ++n) {
    int c = col0 + n * 16 + lr;
    asv[n] = a_src[c];
    adv[n] = a_dst[c];
  }

  #pragma unroll
  for (int m = 0; m < 4; ++m) {
    float ps[4] = {0.f, 0.f, 0.f, 0.f};
    float pd[4] = {0.f, 0.f, 0.f, 0.f};
    #pragma unroll
    for (int n = 0; n < 4; ++n) {
      int col = col0 + n * 16 + lr;
      #pragma unroll
      for (int j = 0; j < 4; ++j) {
        int row = row0 + m * 16 + lk * 4 + j;
        float v = acc[m][n][j];
        if (row < NNODES)
          Hb[(size_t)row * DOUT + col] = f2b(v);
        ps[j] = fmaf(v, asv[n], ps[j]);
        pd[j] = fmaf(v, adv[n], pd[j]);
      }
    }
    #pragma unroll
    for (int off = 1; off < 16; off <<= 1) {
      #pragma unroll
      for (int j = 0; j < 4; ++j) {
        ps[j] += __shfl_xor(ps[j], off);
        pd[j] += __shfl_xor(pd[j], off);
      }
    }
    if (lr == 0) {
      #pragma unroll
      for (int j = 0; j < 4; ++j) {
        s_ps[wv][m * 16 + lk * 4 + j] = ps[j];
        s_pd[wv][m * 16 + lk * 4 + j] = pd[j];
      }
    }
  }

  __syncthreads();
  const int t = threadIdx.x;
  if (t < 64) {
    int row = row0 + t;
    if (row < NNODES) {
      asn[row] = s_ps[0][t] + s_ps[1][t] + s_ps[2][t] + s_ps[3][t];
      adn[row] = s_pd[0][t] + s_pd[1][t] + s_pd[2][t] + s_pd[3][t];
    }
  }
}

// standalone gemm (layers 2,3)
template<int DIN>
__global__ __launch_bounds__(256) void k_gemm_mfma(
    const unsigned short* __restrict__ Ab, const unsigned short* __restrict__ Wt,
    const float* __restrict__ a_src, const float* __restrict__ a_dst,
    unsigned short* __restrict__ Hb, float* __restrict__ asn, float* __restrict__ adn)
{
  __shared__ float s_ps[4][64];
  __shared__ float s_pd[4][64];
  gemm_body<DIN>(blockIdx.x, Ab, Wt, a_src, a_dst, Hb, asn, adn, s_ps, s_pd);
}

// ---------------- fat mid kernel: unbucket (src-chunk counting sort) || gemm1 ----------------
// unbucket orders each dst's edge list by src-chunk (src>>CHKSH): the agg
// gather then sweeps Hb in ~4MB phases -> per-XCD L2-resident working set.
__global__ __launch_bounds__(256) void k_mid(
    const int2* __restrict__ bbuf, const int* __restrict__ bcnt,
    const int* __restrict__ rowptr, int* __restrict__ esrc,
    const unsigned short* __restrict__ Xb, const unsigned short* __restrict__ W1t,
    const float* __restrict__ a_src, const float* __restrict__ a_dst,
    unsigned short* __restrict__ Hb, float* __restrict__ asn, float* __restrict__ adn)
{
  __shared__ float s_ps[4][64];
  __shared__ float s_pd[4][64];
  __shared__ int h2[256][NCHK];
  if (blockIdx.x < NB) {
    const int b = blockIdx.x;
    const int t = threadIdx.x;
    for (int i = t; i < 256 * NCHK; i += 256) (&h2[0][0])[i] = 0;
    __syncthreads();
    const int cnt = bcnt[b];
    const int2* __restrict__ bp = bbuf + (size_t)b * BCAP;
    // pass 1: per-(dst,chunk) counts
    for (int i = t; i < cnt; i += 256) {
      const int2 sd = bp[i];
      atomicAdd(&h2[sd.y & 255][sd.x >> CHKSH], 1);
    }
    __syncthreads();
    // per-dst exclusive scan over chunks (thread t owns dst t)
    {
      int run = 0;
      #pragma unroll
      for (int c = 0; c < NCHK; ++c) {
        const int v = h2[t][c];
        h2[t][c] = run;
        run += v;
      }
    }
    __syncthreads();
    // pass 2: place (chunk-ordered within each dst)
    for (int i = t; i < cnt; i += 256) {
      const int2 sd = bp[i];
      const int pos = rowptr[sd.y] + atomicAdd(&h2[sd.y & 255][sd.x >> CHKSH], 1);
      esrc[pos] = sd.x;
    }
    return;
  }
  gemm_body<512>(blockIdx.x - NB, Xb, W1t, a_src, a_dst, Hb, asn, adn, s_ps, s_pd);
}

// ---------------- attention softmax + aggregation (single sweep) ----------------
// WXB=0 skips the bf16 mirror write (layer 3: nothing consumes it).
template<int MODE, int WXB>
__global__ __launch_bounds__(256) void k_agg(
    const unsigned short* __restrict__ Hb, const int* __restrict__ rowptr,
    const int* __restrict__ esrc, const float* __restrict__ asn,
    const float* __restrict__ adn, const float* __restrict__ bias,
    const float* __restrict__ base, float* __restrict__ out,
    unsigned short* __restrict__ outb)
{
  const int lane = threadIdx.x & 63;
  const int wv = threadIdx.x >> 6;
  const int n = blockIdx.x * 4 + wv;
  if (n >= NNODES) return;
  const int start = rowptr[n];
  const int end = rowptr[n + 1];
  const float adv = adn[n];

  const int q = lane >> 4;
  const int c16 = lane & 15;
  const unsigned short* __restrict__ hb0 = Hb + c16 * 8;
  const unsigned short* __restrict__ hb1 = Hb + 128 + c16 * 8;

  float m = -1e30f, s = 0.f;
  float acc[16];
  #pragma unroll
  for (int k = 0; k < 16; ++k) acc[k] = 0.f;

  for (int c0 = start; c0 < end; c0 += 64) {
    const int i = c0 + lane;
    int msrc = 0;
    float e = -1e30f;
    if (i < end) {
      msrc = esrc[i];
      e = lrelu(asn[msrc] + adv);
    }
    float cm = e;
    #pragma unroll
    for (int off = 32; off > 0; off >>= 1) cm = fmaxf(cm, __shfl_xor(cm, off));
    const float mn = fmaxf(m, cm);
    const float resc = __expf(m - mn);
    s *= resc;
    #pragma unroll
    for (int k = 0; k < 16; ++k) acc[k] *= resc;
    m = mn;
    float p = __expf(e - mn);
    float cs = p;
    #pragma unroll
    for (int off = 32; off > 0; off >>= 1) cs += __shfl_xor(cs, off);
    s += cs;

    const int cnt = min(64, end - c0);
    const int qcnt = (cnt + 3) >> 2;
    for (int jj = 0; jj < qcnt; jj += 2) {
      const int e0 = 4 * jj + q;
      const int e1 = e0 + 4;
      const int s0 = (e0 < cnt) ? e0 : 0;
      const int s1 = (e1 < cnt) ? e1 : 0;
      float a0 = __shfl(p, s0);
      const int sj0 = __shfl(msrc, s0);
      float a1 = __shfl(p, s1);
      const int sj1 = __shfl(msrc, s1);
      if (e0 >= cnt) a0 = 0.f;
      if (jj + 1 >= qcnt || e1 >= cnt) a1 = 0.f;
      if (a0 != 0.f) {
        const u16x8 h00 = *reinterpret_cast<const u16x8*>(hb0 + (size_t)sj0 * DOUT);
        const u16x8 h01 = *reinterpret_cast<const u16x8*>(hb1 + (size_t)sj0 * DOUT);
        #pragma unroll
        for (int k = 0; k < 8; ++k) {
          acc[k]     = fmaf(a0, b2f((unsigned short)h00[k]), acc[k]);
          acc[k + 8] = fmaf(a0, b2f((unsigned short)h01[k]), acc[k + 8]);
        }
      }
      if (a1 != 0.f) {
        const u16x8 h10 = *reinterpret_cast<const u16x8*>(hb0 + (size_t)sj1 * DOUT);
        const u16x8 h11 = *reinterpret_cast<const u16x8*>(hb1 + (size_t)sj1 * DOUT);
        #pragma unroll
        for (int k = 0; k < 8; ++k) {
          acc[k]     = fmaf(a1, b2f((unsigned short)h10[k]), acc[k]);
          acc[k + 8] = fmaf(a1, b2f((unsigned short)h11[k]), acc[k + 8]);
        }
      }
    }
  }

  #pragma unroll
  for (int k = 0; k < 16; ++k) {
    acc[k] += __shfl_xor(acc[k], 16);
    acc[k] += __shfl_xor(acc[k], 32);
  }

  if (lane < 16) {
    const float inv = 1.f / (s + 1e-16f);
    const int cb = c16 * 8;
    float o[16];
    #pragma unroll
    for (int k = 0; k < 8; ++k) {
      o[k]     = fmaxf(acc[k] * inv + bias[cb + k], 0.f);
      o[k + 8] = fmaxf(acc[k + 8] * inv + bias[128 + cb + k], 0.f);
    }
    if (MODE == 1) {
      #pragma unroll
      for (int k = 0; k < 8; ++k) {
        o[k]     += base[(size_t)n * DOUT + cb + k];
        o[k + 8] += base[(size_t)n * DOUT + 128 + cb + k];
      }
    }
    *reinterpret_cast<float4*>(out + (size_t)n * DOUT + cb)           = make_float4(o[0], o[1], o[2], o[3]);
    *reinterpret_cast<float4*>(out + (size_t)n * DOUT + cb + 4)       = make_float4(o[4], o[5], o[6], o[7]);
    *reinterpret_cast<float4*>(out + (size_t)n * DOUT + 128 + cb)     = make_float4(o[8], o[9], o[10], o[11]);
    *reinterpret_cast<float4*>(out + (size_t)n * DOUT + 128 + cb + 4) = make_float4(o[12], o[13], o[14], o[15]);
    if (WXB) {
      u16x8 ob0, ob1;
      #pragma unroll
      for (int k = 0; k < 8; ++k) { ob0[k] = f2b(o[k]); ob1[k] = f2b(o[k + 8]); }
      *reinterpret_cast<u16x8*>(outb + (size_t)n * DOUT + cb)       = ob0;
      *reinterpret_cast<u16x8*>(outb + (size_t)n * DOUT + 128 + cb) = ob1;
    }
  }
}

// ---------------- launch ----------------
extern "C" void kernel_launch(void* const* d_in, const int* in_sizes, int n_in,
                              void* d_out, int out_size, void* d_ws, size_t ws_size,
                              hipStream_t stream) {
  const float* x   = (const float*)d_in[0];
  const int*   ei  = (const int*)d_in[1];
  const float* W1  = (const float*)d_in[2];
  const float* as1 = (const float*)d_in[3];
  const float* ad1 = (const float*)d_in[4];
  const float* b1  = (const float*)d_in[5];
  const float* W2  = (const float*)d_in[6];
  const float* as2 = (const float*)d_in[7];
  const float* ad2 = (const float*)d_in[8];
  const float* b2  = (const float*)d_in[9];
  const float* W3  = (const float*)d_in[10];
  const float* as3 = (const float*)d_in[11];
  const float* ad3 = (const float*)d_in[12];
  const float* b3  = (const float*)d_in[13];
  float* out = (float*)d_out;   // doubles as fp32 layer output

  char* ws = (char*)d_ws;
  size_t off = 0;
  auto alloc = [&](size_t bytes) -> void* {
    void* p = ws + off;
    off = (off + bytes + 255) & ~(size_t)255;
    return p;
  };
  unsigned short* Xb   = (unsigned short*)alloc((size_t)NNODES * 512 * sizeof(unsigned short));
  unsigned short* Hb   = (unsigned short*)alloc((size_t)NNODES * DOUT * sizeof(unsigned short));
  unsigned short* W1t  = (unsigned short*)alloc((size_t)512 * DOUT * sizeof(unsigned short));
  unsigned short* W2t  = (unsigned short*)alloc((size_t)DOUT * DOUT * sizeof(unsigned short));
  unsigned short* W3t  = (unsigned short*)alloc((size_t)DOUT * DOUT * sizeof(unsigned short));
  float* asn  = (float*)alloc(NNODES * sizeof(float));
  float* adn  = (float*)alloc(NNODES * sizeof(float));
  int*   deg  = (int*)alloc(NNODES * sizeof(int));
  int*   rowptr = (int*)alloc((NNODES + 1) * sizeof(int));
  int*   bsum = (int*)alloc(SCANB * sizeof(int));
  int*   bexcl = (int*)alloc(SCANB * sizeof(int));
  int*   bcnt = (int*)alloc(NB * sizeof(int));
  int*   esrc = (int*)alloc((size_t)(NEDGES + NNODES) * sizeof(int));
  int2*  bbuf = (int2*)alloc((size_t)NB * BCAP * sizeof(int2));

  hipMemsetAsync(deg, 0, NNODES * sizeof(int), stream);
  hipMemsetAsync(bcnt, 0, NB * sizeof(int), stream);

  // fat pre: bucket || castX || castW1-3
  const int preGrid = BBUCKET + BCASTX + 512 + 256 + 256;
  k_pre<<<preGrid, 256, 0, stream>>>(ei, deg, bcnt, bbuf,
                                     (const float4*)x, (ushort4*)Xb,
                                     W1, W1t, W2, W2t, W3, W3t);
  k_scan1<<<SCANB, 256, 0, stream>>>(deg, rowptr, bsum);
  k_scan2<<<1, 256, 0, stream>>>(bsum, bexcl);
  k_scan3<<<SCANB, 256, 0, stream>>>(rowptr, bexcl);

  // fat mid: unbucket (chunk sort) || gemm layer 1
  k_mid<<<NB + GEMM_GRID, 256, 0, stream>>>(bbuf, bcnt, rowptr, esrc,
                                            Xb, W1t, as1, ad1, Hb, asn, adn);

  const int aggGrid = (NNODES + 3) / 4;

  // layer 1
  k_agg<0, 1><<<aggGrid, 256, 0, stream>>>(Hb, rowptr, esrc, asn, adn, b1, nullptr, out, Xb);
  // layer 2 (Xb holds bf16 of layer-1 output)
  k_gemm_mfma<256><<<GEMM_GRID, 256, 0, stream>>>(Xb, W2t, as2, ad2, Hb, asn, adn);
  k_agg<1, 1><<<aggGrid, 256, 0, stream>>>(Hb, rowptr, esrc, asn, adn, b2, out, out, Xb);
  // layer 3 (no bf16 mirror needed)
  k_gemm_mfma<256><<<GEMM_GRID, 256, 0, stream>>>(Xb, W3t, as3, ad3, Hb, asn, adn);
  k_agg<1, 0><<<aggGrid, 256, 0, stream>>>(Hb, rowptr, esrc, asn, adn, b3, out, out, Xb);
}

// Round 12
// 580.099 us; speedup vs baseline: 2.7522x; 1.0264x over previous
//
#include <hip/hip_runtime.h>
#include <math.h>

#define NNODES 50000
#define NEDGES 1600000
#define DOUT 256
#define NEG_SLOPE 0.2f
#define SCANB ((NNODES + 255) / 256)
#define NB ((NNODES + 255) / 256)   // dst buckets of 256 nodes (196)
#define BCAP 10240                  // bucket capacity (mean ~8420, >15 sigma margin)
#define CHUNK 8192                  // edges per bucket block
#define BBUCKET ((NEDGES + NNODES + CHUNK - 1) / CHUNK)   // 202
#define BCASTX 2048
#define GEMM_GRID ((NNODES + 63) / 64)                    // 782

typedef __attribute__((ext_vector_type(8))) short short8;
typedef __attribute__((ext_vector_type(8))) unsigned short u16x8;
typedef __attribute__((ext_vector_type(4))) float f32x4;

__device__ __forceinline__ float lrelu(float e) { return e > 0.f ? e : NEG_SLOPE * e; }
__device__ __forceinline__ float b2f(unsigned short u) {
  union { unsigned u; float f; } c; c.u = ((unsigned)u) << 16; return c.f;
}
__device__ __forceinline__ unsigned short f2b(float f) {
  union { float f; unsigned u; } c; c.f = f;
  return (unsigned short)((c.u + 0x7fffu + ((c.u >> 16) & 1u)) >> 16);
}

// ---------------- fat pre kernel: bucket || castX || castW1-3 ----------------
__device__ void castW_body(int bid, int DIN, const float* __restrict__ W,
                           unsigned short* __restrict__ Wt) {
  const int idx = bid * 256 + threadIdx.x;
  if (idx >= DIN * DOUT) return;
  const int k = idx / DOUT, n = idx % DOUT;
  Wt[n * DIN + k] = f2b(W[idx]);
}

__global__ __launch_bounds__(256) void k_pre(
    const int* __restrict__ ei, int* __restrict__ deg, int* __restrict__ bcnt,
    int2* __restrict__ bbuf, const float4* __restrict__ x4, ushort4* __restrict__ xb4,
    const float* __restrict__ W1, unsigned short* __restrict__ W1t,
    const float* __restrict__ W2, unsigned short* __restrict__ W2t,
    const float* __restrict__ W3, unsigned short* __restrict__ W3t)
{
  __shared__ int hcnt[NB];
  __shared__ int lpos[NB];
  int b = blockIdx.x;
  const int t = threadIdx.x;

  if (b < BBUCKET) {
    // bucket: per-block LDS histogram -> one reserve atomic per (block,bucket)
    // -> block-private contiguous sub-segment writes (L2-merged lines).
    const int e0 = b * CHUNK;
    const int EP = NEDGES + NNODES;
    const int ecnt = min(CHUNK, EP - e0);
    for (int i = t; i < NB; i += 256) hcnt[i] = 0;
    __syncthreads();
    for (int i = t; i < ecnt; i += 256) {
      const int e = e0 + i;
      int dst = (e < NEDGES) ? ei[NEDGES + e] : (e - NEDGES);
      atomicAdd(&deg[dst], 1);
      atomicAdd(&hcnt[dst >> 8], 1);
    }
    __syncthreads();
    for (int bb = t; bb < NB; bb += 256) {
      const int c = hcnt[bb];
      lpos[bb] = (c > 0) ? atomicAdd(&bcnt[bb], c) : 0;
    }
    __syncthreads();
    for (int i = t; i < ecnt; i += 256) {
      const int e = e0 + i;
      int src, dst;
      if (e < NEDGES) { src = ei[e]; dst = ei[NEDGES + e]; }
      else            { src = e - NEDGES; dst = src; }
      const int bb = dst >> 8;
      const int p = atomicAdd(&lpos[bb], 1);
      bbuf[(size_t)bb * BCAP + p] = make_int2(src, dst);
    }
    return;
  }
  b -= BBUCKET;
  if (b < BCASTX) {
    const int n4 = NNODES * 512 / 4;
    for (int i = b * 256 + t; i < n4; i += BCASTX * 256) {
      float4 v = x4[i];
      ushort4 o;
      o.x = f2b(v.x); o.y = f2b(v.y); o.z = f2b(v.z); o.w = f2b(v.w);
      xb4[i] = o;
    }
    return;
  }
  b -= BCASTX;
  if (b < 512) { castW_body(b, 512, W1, W1t); return; }
  b -= 512;
  if (b < 256) { castW_body(b, 256, W2, W2t); return; }
  b -= 256;
  castW_body(b, 256, W3, W3t);
}

// ---------------- scans ----------------
__global__ __launch_bounds__(256) void k_scan1(const int* __restrict__ deg,
                                               int* __restrict__ rowptr,
                                               int* __restrict__ bsum) {
  __shared__ int wsum[4];
  const int t = threadIdx.x, lane = t & 63, w = t >> 6;
  const int i = blockIdx.x * 256 + t;
  int x = (i < NNODES) ? deg[i] : 0;
  #pragma unroll
  for (int off = 1; off < 64; off <<= 1) {
    int y = __shfl_up(x, off);
    if (lane >= off) x += y;
  }
  if (lane == 63) wsum[w] = x;
  __syncthreads();
  int s0 = wsum[0], s1 = wsum[1], s2 = wsum[2], s3 = wsum[3];
  int woff = (w > 0 ? s0 : 0) + (w > 1 ? s1 : 0) + (w > 2 ? s2 : 0);
  if (i < NNODES) rowptr[i + 1] = woff + x;
  if (t == 255) bsum[blockIdx.x] = woff + x;
}

__global__ __launch_bounds__(256) void k_scan2(int* __restrict__ bsum,
                                               int* __restrict__ bexcl) {
  __shared__ int wsum[4];
  const int t = threadIdx.x, lane = t & 63, w = t >> 6;
  int v = (t < SCANB) ? bsum[t] : 0;
  int x = v;
  #pragma unroll
  for (int off = 1; off < 64; off <<= 1) {
    int y = __shfl_up(x, off);
    if (lane >= off) x += y;
  }
  if (lane == 63) wsum[w] = x;
  __syncthreads();
  int s0 = wsum[0], s1 = wsum[1], s2 = wsum[2], s3 = wsum[3];
  int woff = (w > 0 ? s0 : 0) + (w > 1 ? s1 : 0) + (w > 2 ? s2 : 0);
  if (t < SCANB) bexcl[t] = woff + x - v;
}

__global__ __launch_bounds__(256) void k_scan3(int* __restrict__ rowptr,
                                               const int* __restrict__ bexcl) {
  const int i = blockIdx.x * 256 + threadIdx.x;
  if (i == 0) rowptr[0] = 0;
  if (i < NNODES) rowptr[i + 1] += bexcl[blockIdx.x];
}

// ---------------- GEMM body (device) ----------------
template<int DIN>
__device__ void gemm_body(int bid,
    const unsigned short* __restrict__ Ab, const unsigned short* __restrict__ Wt,
    const float* __restrict__ a_src, const float* __restrict__ a_dst,
    unsigned short* __restrict__ Hb, float* __restrict__ asn, float* __restrict__ adn,
    float (*s_ps)[64], float (*s_pd)[64])
{
  const int lane = threadIdx.x & 63;
  const int wv = threadIdx.x >> 6;
  const int row0 = bid * 64;
  const int col0 = wv * 64;
  const int lr = lane & 15;
  const int lk = lane >> 4;

  f32x4 acc[4][4];
  #pragma unroll
  for (int m = 0; m < 4; ++m)
    #pragma unroll
    for (int n = 0; n < 4; ++n)
      acc[m][n] = (f32x4){0.f, 0.f, 0.f, 0.f};

  const unsigned short* arow[4];
  #pragma unroll
  for (int m = 0; m < 4; ++m) {
    int r = row0 + m * 16 + lr;
    if (r > NNODES - 1) r = NNODES - 1;
    arow[m] = Ab + (size_t)r * DIN + lk * 8;
  }
  const unsigned short* brow[4];
  #pragma unroll
  for (int n = 0; n < 4; ++n)
    brow[n] = Wt + (size_t)(col0 + n * 16 + lr) * DIN + lk * 8;

  for (int k = 0; k < DIN; k += 32) {
    short8 aF[4], bF[4];
    #pragma unroll
    for (int m = 0; m < 4; ++m)
      aF[m] = *reinterpret_cast<const short8*>(arow[m] + k);
    #pragma unroll
    for (int n = 0; n < 4; ++n)
      bF[n] = *reinterpret_cast<const short8*>(brow[n] + k);
    #pragma unroll
    for (int m = 0; m < 4; ++m)
      #pragma unroll
      for (int n = 0; n < 4; ++n)
        acc[m][n] = __builtin_amdgcn_mfma_f32_16x16x32_bf16(aF[m], bF[n], acc[m][n], 0, 0, 0);
  }

  float asv[4], adv[4];
  #pragma unroll
  for (int n = 0; n < 4; ++n) {
    int c = col0 + n * 16 + lr;
    asv[n] = a_src[c];
    adv[n] = a_dst[c];
  }

  #pragma unroll
  for (int m = 0; m < 4; ++m) {
    float ps[4] = {0.f, 0.f, 0.f, 0.f};
    float pd[4] = {0.f, 0.f, 0.f, 0.f};
    #pragma unroll
    for (int n = 0; n < 4; ++n) {
      int col = col0 + n * 16 + lr;
      #pragma unroll
      for (int j = 0; j < 4; ++j) {
        int row = row0 + m * 16 + lk * 4 + j;
        float v = acc[m][n][j];
        if (row < NNODES)
          Hb[(size_t)row * DOUT + col] = f2b(v);
        ps[j] = fmaf(v, asv[n], ps[j]);
        pd[j] = fmaf(v, adv[n], pd[j]);
      }
    }
    #pragma unroll
    for (int off = 1; off < 16; off <<= 1) {
      #pragma unroll
      for (int j = 0; j < 4; ++j) {
        ps[j] += __shfl_xor(ps[j], off);
        pd[j] += __shfl_xor(pd[j], off);
      }
    }
    if (lr == 0) {
      #pragma unroll
      for (int j = 0; j < 4; ++j) {
        s_ps[wv][m * 16 + lk * 4 + j] = ps[j];
        s_pd[wv][m * 16 + lk * 4 + j] = pd[j];
      }
    }
  }

  __syncthreads();
  const int t = threadIdx.x;
  if (t < 64) {
    int row = row0 + t;
    if (row < NNODES) {
      asn[row] = s_ps[0][t] + s_ps[1][t] + s_ps[2][t] + s_ps[3][t];
      adn[row] = s_pd[0][t] + s_pd[1][t] + s_pd[2][t] + s_pd[3][t];
    }
  }
}

// standalone gemm (layers 2,3)
template<int DIN>
__global__ __launch_bounds__(256) void k_gemm_mfma(
    const unsigned short* __restrict__ Ab, const unsigned short* __restrict__ Wt,
    const float* __restrict__ a_src, const float* __restrict__ a_dst,
    unsigned short* __restrict__ Hb, float* __restrict__ asn, float* __restrict__ adn)
{
  __shared__ float s_ps[4][64];
  __shared__ float s_pd[4][64];
  gemm_body<DIN>(blockIdx.x, Ab, Wt, a_src, a_dst, Hb, asn, adn, s_ps, s_pd);
}

// ---------------- fat mid kernel: unbucket || gemm1 ----------------
__global__ __launch_bounds__(256) void k_mid(
    const int2* __restrict__ bbuf, const int* __restrict__ bcnt,
    const int* __restrict__ rowptr, int* __restrict__ esrc,
    const unsigned short* __restrict__ Xb, const unsigned short* __restrict__ W1t,
    const float* __restrict__ a_src, const float* __restrict__ a_dst,
    unsigned short* __restrict__ Hb, float* __restrict__ asn, float* __restrict__ adn)
{
  __shared__ float s_ps[4][64];
  __shared__ float s_pd[4][64];
  __shared__ int fill[256];
  if (blockIdx.x < NB) {
    // unbucket: contiguous esrc region per block -> L2-merged writes
    const int b = blockIdx.x;
    fill[threadIdx.x] = 0;
    __syncthreads();
    const int cnt = bcnt[b];
    const int2* __restrict__ bp = bbuf + (size_t)b * BCAP;
    for (int i = threadIdx.x; i < cnt; i += 256) {
      const int2 sd = bp[i];
      const int pos = rowptr[sd.y] + atomicAdd(&fill[sd.y & 255], 1);
      esrc[pos] = sd.x;
    }
    return;
  }
  gemm_body<512>(blockIdx.x - NB, Xb, W1t, a_src, a_dst, Hb, asn, adn, s_ps, s_pd);
}

// ---------------- attention softmax + aggregation (single sweep) ----------------
// Residual chain kept in bf16: MODE=1 reads bf16 base; OUT32=1 writes the final
// fp32 output (layer 3), otherwise only the bf16 row (next layer's GEMM input).
template<int MODE, int OUT32>
__global__ __launch_bounds__(256) void k_agg(
    const unsigned short* __restrict__ Hb, const int* __restrict__ rowptr,
    const int* __restrict__ esrc, const float* __restrict__ asn,
    const float* __restrict__ adn, const float* __restrict__ bias,
    const unsigned short* __restrict__ baseb, float* __restrict__ out,
    unsigned short* __restrict__ outb)
{
  const int lane = threadIdx.x & 63;
  const int wv = threadIdx.x >> 6;
  const int n = blockIdx.x * 4 + wv;
  if (n >= NNODES) return;
  const int start = rowptr[n];
  const int end = rowptr[n + 1];
  const float adv = adn[n];

  const int q = lane >> 4;
  const int c16 = lane & 15;
  const unsigned short* __restrict__ hb0 = Hb + c16 * 8;
  const unsigned short* __restrict__ hb1 = Hb + 128 + c16 * 8;

  float m = -1e30f, s = 0.f;
  float acc[16];
  #pragma unroll
  for (int k = 0; k < 16; ++k) acc[k] = 0.f;

  for (int c0 = start; c0 < end; c0 += 64) {
    const int i = c0 + lane;
    int msrc = 0;
    float e = -1e30f;
    if (i < end) {
      msrc = esrc[i];
      e = lrelu(asn[msrc] + adv);
    }
    float cm = e;
    #pragma unroll
    for (int off = 32; off > 0; off >>= 1) cm = fmaxf(cm, __shfl_xor(cm, off));
    const float mn = fmaxf(m, cm);
    const float resc = __expf(m - mn);
    s *= resc;
    #pragma unroll
    for (int k = 0; k < 16; ++k) acc[k] *= resc;
    m = mn;
    float p = __expf(e - mn);
    float cs = p;
    #pragma unroll
    for (int off = 32; off > 0; off >>= 1) cs += __shfl_xor(cs, off);
    s += cs;

    const int cnt = min(64, end - c0);
    const int qcnt = (cnt + 3) >> 2;
    for (int jj = 0; jj < qcnt; jj += 2) {
      const int e0 = 4 * jj + q;
      const int e1 = e0 + 4;
      const int s0 = (e0 < cnt) ? e0 : 0;
      const int s1 = (e1 < cnt) ? e1 : 0;
      float a0 = __shfl(p, s0);
      const int sj0 = __shfl(msrc, s0);
      float a1 = __shfl(p, s1);
      const int sj1 = __shfl(msrc, s1);
      if (e0 >= cnt) a0 = 0.f;
      if (jj + 1 >= qcnt || e1 >= cnt) a1 = 0.f;
      if (a0 != 0.f) {
        const u16x8 h00 = *reinterpret_cast<const u16x8*>(hb0 + (size_t)sj0 * DOUT);
        const u16x8 h01 = *reinterpret_cast<const u16x8*>(hb1 + (size_t)sj0 * DOUT);
        #pragma unroll
        for (int k = 0; k < 8; ++k) {
          acc[k]     = fmaf(a0, b2f((unsigned short)h00[k]), acc[k]);
          acc[k + 8] = fmaf(a0, b2f((unsigned short)h01[k]), acc[k + 8]);
        }
      }
      if (a1 != 0.f) {
        const u16x8 h10 = *reinterpret_cast<const u16x8*>(hb0 + (size_t)sj1 * DOUT);
        const u16x8 h11 = *reinterpret_cast<const u16x8*>(hb1 + (size_t)sj1 * DOUT);
        #pragma unroll
        for (int k = 0; k < 8; ++k) {
          acc[k]     = fmaf(a1, b2f((unsigned short)h10[k]), acc[k]);
          acc[k + 8] = fmaf(a1, b2f((unsigned short)h11[k]), acc[k + 8]);
        }
      }
    }
  }

  #pragma unroll
  for (int k = 0; k < 16; ++k) {
    acc[k] += __shfl_xor(acc[k], 16);
    acc[k] += __shfl_xor(acc[k], 32);
  }

  if (lane < 16) {
    const float inv = 1.f / (s + 1e-16f);
    const int cb = c16 * 8;
    float o[16];
    #pragma unroll
    for (int k = 0; k < 8; ++k) {
      o[k]     = fmaxf(acc[k] * inv + bias[cb + k], 0.f);
      o[k + 8] = fmaxf(acc[k + 8] * inv + bias[128 + cb + k], 0.f);
    }
    if (MODE == 1) {
      const u16x8 r0 = *reinterpret_cast<const u16x8*>(baseb + (size_t)n * DOUT + cb);
      const u16x8 r1 = *reinterpret_cast<const u16x8*>(baseb + (size_t)n * DOUT + 128 + cb);
      #pragma unroll
      for (int k = 0; k < 8; ++k) {
        o[k]     += b2f((unsigned short)r0[k]);
        o[k + 8] += b2f((unsigned short)r1[k]);
      }
    }
    if (OUT32) {
      *reinterpret_cast<float4*>(out + (size_t)n * DOUT + cb)           = make_float4(o[0], o[1], o[2], o[3]);
      *reinterpret_cast<float4*>(out + (size_t)n * DOUT + cb + 4)       = make_float4(o[4], o[5], o[6], o[7]);
      *reinterpret_cast<float4*>(out + (size_t)n * DOUT + 128 + cb)     = make_float4(o[8], o[9], o[10], o[11]);
      *reinterpret_cast<float4*>(out + (size_t)n * DOUT + 128 + cb + 4) = make_float4(o[12], o[13], o[14], o[15]);
    } else {
      u16x8 ob0, ob1;
      #pragma unroll
      for (int k = 0; k < 8; ++k) { ob0[k] = f2b(o[k]); ob1[k] = f2b(o[k + 8]); }
      *reinterpret_cast<u16x8*>(outb + (size_t)n * DOUT + cb)       = ob0;
      *reinterpret_cast<u16x8*>(outb + (size_t)n * DOUT + 128 + cb) = ob1;
    }
  }
}

// ---------------- launch ----------------
extern "C" void kernel_launch(void* const* d_in, const int* in_sizes, int n_in,
                              void* d_out, int out_size, void* d_ws, size_t ws_size,
                              hipStream_t stream) {
  const float* x   = (const float*)d_in[0];
  const int*   ei  = (const int*)d_in[1];
  const float* W1  = (const float*)d_in[2];
  const float* as1 = (const float*)d_in[3];
  const float* ad1 = (const float*)d_in[4];
  const float* b1  = (const float*)d_in[5];
  const float* W2  = (const float*)d_in[6];
  const float* as2 = (const float*)d_in[7];
  const float* ad2 = (const float*)d_in[8];
  const float* b2  = (const float*)d_in[9];
  const float* W3  = (const float*)d_in[10];
  const float* as3 = (const float*)d_in[11];
  const float* ad3 = (const float*)d_in[12];
  const float* b3  = (const float*)d_in[13];
  float* out = (float*)d_out;   // final fp32 output only

  char* ws = (char*)d_ws;
  size_t off = 0;
  auto alloc = [&](size_t bytes) -> void* {
    void* p = ws + off;
    off = (off + bytes + 255) & ~(size_t)255;
    return p;
  };
  unsigned short* Xb   = (unsigned short*)alloc((size_t)NNODES * 512 * sizeof(unsigned short));
  unsigned short* Hb   = (unsigned short*)alloc((size_t)NNODES * DOUT * sizeof(unsigned short));
  unsigned short* W1t  = (unsigned short*)alloc((size_t)512 * DOUT * sizeof(unsigned short));
  unsigned short* W2t  = (unsigned short*)alloc((size_t)DOUT * DOUT * sizeof(unsigned short));
  unsigned short* W3t  = (unsigned short*)alloc((size_t)DOUT * DOUT * sizeof(unsigned short));
  float* asn  = (float*)alloc(NNODES * sizeof(float));
  float* adn  = (float*)alloc(NNODES * sizeof(float));
  // deg + bcnt adjacent -> single memset
  int*   deg  = (int*)alloc(NNODES * sizeof(int) + NB * sizeof(int) + 256);
  int*   bcnt = deg + NNODES;
  int*   rowptr = (int*)alloc((NNODES + 1) * sizeof(int));
  int*   bsum = (int*)alloc(SCANB * sizeof(int));
  int*   bexcl = (int*)alloc(SCANB * sizeof(int));
  int*   esrc = (int*)alloc((size_t)(NEDGES + NNODES) * sizeof(int));
  int2*  bbuf = (int2*)alloc((size_t)NB * BCAP * sizeof(int2));

  hipMemsetAsync(deg, 0, (NNODES + NB) * sizeof(int), stream);

  // fat pre: bucket || castX || castW1-3
  const int preGrid = BBUCKET + BCASTX + 512 + 256 + 256;
  k_pre<<<preGrid, 256, 0, stream>>>(ei, deg, bcnt, bbuf,
                                     (const float4*)x, (ushort4*)Xb,
                                     W1, W1t, W2, W2t, W3, W3t);
  k_scan1<<<SCANB, 256, 0, stream>>>(deg, rowptr, bsum);
  k_scan2<<<1, 256, 0, stream>>>(bsum, bexcl);
  k_scan3<<<SCANB, 256, 0, stream>>>(rowptr, bexcl);

  // fat mid: unbucket || gemm layer 1
  k_mid<<<NB + GEMM_GRID, 256, 0, stream>>>(bbuf, bcnt, rowptr, esrc,
                                            Xb, W1t, as1, ad1, Hb, asn, adn);

  const int aggGrid = (NNODES + 3) / 4;

  // layer 1: Xb <- bf16 row (no fp32 mirror)
  k_agg<0, 0><<<aggGrid, 256, 0, stream>>>(Hb, rowptr, esrc, asn, adn, b1, nullptr, nullptr, Xb);
  // layer 2: in-place bf16 residual update of Xb
  k_gemm_mfma<256><<<GEMM_GRID, 256, 0, stream>>>(Xb, W2t, as2, ad2, Hb, asn, adn);
  k_agg<1, 0><<<aggGrid, 256, 0, stream>>>(Hb, rowptr, esrc, asn, adn, b2, Xb, nullptr, Xb);
  // layer 3: final fp32 output
  k_gemm_mfma<256><<<GEMM_GRID, 256, 0, stream>>>(Xb, W3t, as3, ad3, Hb, asn, adn);
  k_agg<1, 1><<<aggGrid, 256, 0, stream>>>(Hb, rowptr, esrc, asn, adn, b3, Xb, out, nullptr);
}